// Round 7
// baseline (138.733 us; speedup 1.0000x reference)
//
#include <hip/hip_runtime.h>
#include <hip/hip_bf16.h>
#include <math.h>

#define B_ 4
#define T_ 64
#define N_ 2048
#define C_ 32
#define H_ 64
#define M_ (B_*N_)      // 8192
#define SPB 32          // samples per block: TWO independent 16-row tiles
#define SLOPE 0.2f

typedef __attribute__((ext_vector_type(8))) short short8;   // 8 bf16 (4 VGPRs)
typedef __attribute__((ext_vector_type(4))) float floatx4;  // MFMA acc

#define MFMA16(a,b,c) __builtin_amdgcn_mfma_f32_16x16x32_bf16(a,b,c,0,0,0)

// Barrier without vmcnt drain: LDS visibility via lgkmcnt(0); global prefetch
// loads stay in flight across the barrier. Uniform control flow.
#define BARRIER() asm volatile("s_waitcnt lgkmcnt(0)\n\ts_barrier" ::: "memory")

__device__ __forceinline__ float lrelu(float v) { return v >= 0.f ? v : SLOPE * v; }
__device__ __forceinline__ float fsig(float x)  { return 1.f / (1.f + __expf(-x)); }
__device__ __forceinline__ float ftanh(float x) { return 1.f - 2.f / (__expf(2.f * x) + 1.f); }

__device__ __forceinline__ unsigned short f2bf(float f) {
    union { __hip_bfloat16 b; unsigned short u; } cv;
    cv.b = __float2bfloat16(f);          // hardware cvt (RNE); lo compensates anyway
    return cv.u;
}
__device__ __forceinline__ float bf16_f32(unsigned short s) {
    return __uint_as_float(((unsigned)s) << 16);
}
__device__ __forceinline__ void split2(float f, unsigned short& h, unsigned short& l) {
    h = f2bf(f);
    l = f2bf(f - bf16_f32(h));
}
#define PACK2(h0,h1) ((int)(unsigned)(h0) | ((int)(h1) << 16))

// LDS layout (shorts): h tiles A/B hi/lo double-buffered, x tiles likewise.
#define HB 1024          // 16 samples x 64 cols
#define XB 512           // 64 lanes x 8 channels
#define O_HA_HI(b) ((b)*HB)
#define O_HA_LO(b) (2*HB + (b)*HB)
#define O_HB_HI(b) (4*HB + (b)*HB)
#define O_HB_LO(b) (6*HB + (b)*HB)
#define O_XA_HI(b) (8*HB + (b)*XB)
#define O_XA_LO(b) (8*HB + 2*XB + (b)*XB)
#define O_XB_HI(b) (8*HB + 4*XB + (b)*XB)
#define O_XB_LO(b) (8*HB + 6*XB + (b)*XB)
#define SMEM_SHORTS (8*HB + 8*XB)        // 12288 shorts = 24 KB

__global__ __launch_bounds__(256, 1) void gru_kernel(
    const float* __restrict__ x,      // [B,T,N,C]
    const float* __restrict__ w_ih,   // [192][32]
    const float* __restrict__ w_hh,   // [192][64]
    const float* __restrict__ b_ih,   // [192]
    const float* __restrict__ b_hh,   // [192]
    float* __restrict__ h_last)       // [M][H]  (d_out scratch)
{
    __shared__ short smem[SMEM_SHORTS];

    const int tid   = threadIdx.x;
    const int lane  = tid & 63;
    const int w     = tid >> 6;        // wave 0..3 -> gate-col tiles {w, w+4, w+8}
    const int col16 = lane & 15;
    const int kgrp  = lane >> 4;       // 0..3

    const int m0 = blockIdx.x * SPB;   // 32 samples: tile A = m0.., tile B = m0+16..
    const int b  = m0 >> 11;
    const int n0 = m0 & 2047;

    // ---- weight B-fragments -> registers (once). B[k][col] = w[col][k]. ----
    short8 whh_hi[3][2], whh_lo[3][2], wih_hi[3], wih_lo[3];
    #pragma unroll
    for (int g = 0; g < 3; ++g) {
        const int colj = g*64 + w*16 + col16;
        #pragma unroll
        for (int kb = 0; kb < 2; ++kb) {
            const float* src = w_hh + colj*64 + kb*32 + kgrp*8;
            short8 hi, lo;
            #pragma unroll
            for (int e = 0; e < 8; ++e) {
                unsigned short h_, l_; split2(src[e], h_, l_);
                hi[e] = (short)h_; lo[e] = (short)l_;
            }
            whh_hi[g][kb] = hi; whh_lo[g][kb] = lo;
        }
        {
            const float* src = w_ih + colj*32 + kgrp*8;
            short8 hi, lo;
            #pragma unroll
            for (int e = 0; e < 8; ++e) {
                unsigned short h_, l_; split2(src[e], h_, l_);
                hi[e] = (short)h_; lo[e] = (short)l_;
            }
            wih_hi[g] = hi; wih_lo[g] = lo;
        }
    }

    const int jcol = w*16 + col16;
    const float br  = b_ih[jcol]       + b_hh[jcol];
    const float bz  = b_ih[64 + jcol]  + b_hh[64 + jcol];
    const float bin = b_ih[128 + jcol];
    const float bhn = b_hh[128 + jcol];

    // x staging geometry: per tile each thread handles 2 consecutive channels
    const int fl  = tid >> 2;                 // frag-lane 0..63
    const int row = fl & 15;
    const int kk  = (fl >> 4) * 8 + (tid & 3) * 2;
    const int xii = fl*4 + (tid & 3);
    const float* xsrcA = x + (((size_t)b * T_) * N_ + (n0 + row)) * C_ + kk;
    const float* xsrcB = xsrcA + 16 * C_;

    // ---- prologue: zero h buf0; stage x(0); prefetch x(1) ----
    for (int i = tid; i < 512; i += 256) {
        ((int*)(smem + O_HA_HI(0)))[i] = 0;
        ((int*)(smem + O_HA_LO(0)))[i] = 0;
        ((int*)(smem + O_HB_HI(0)))[i] = 0;
        ((int*)(smem + O_HB_LO(0)))[i] = 0;
    }
    {
        float2 v = *(const float2*)(xsrcA);
        unsigned short h0,l0,h1,l1;
        split2(v.x,h0,l0); split2(v.y,h1,l1);
        ((int*)(smem + O_XA_HI(0)))[xii] = PACK2(h0,h1);
        ((int*)(smem + O_XA_LO(0)))[xii] = PACK2(l0,l1);
        v = *(const float2*)(xsrcB);
        split2(v.x,h0,l0); split2(v.y,h1,l1);
        ((int*)(smem + O_XB_HI(0)))[xii] = PACK2(h0,h1);
        ((int*)(smem + O_XB_LO(0)))[xii] = PACK2(l0,l1);
    }
    float2 pXA = *(const float2*)(xsrcA + N_*C_);   // x(1)
    float2 pXB = *(const float2*)(xsrcB + N_*C_);
    float2 qXA = {0.f,0.f}, qXB = {0.f,0.f};
    BARRIER();

    float hpA[4] = {0.f,0.f,0.f,0.f};
    float hpB[4] = {0.f,0.f,0.f,0.f};

#define GRU_STEP(T, CUR, PXA_, PXB_, QXA_, QXB_) do {                           \
    const int nxt_ = (CUR) ^ 1;                                                 \
    /* ---- ds reads: both tiles' h + x fragments ---- */                       \
    short8 ahA_hi[2], ahA_lo[2], ahB_hi[2], ahB_lo[2];                          \
    _Pragma("unroll")                                                           \
    for (int kb = 0; kb < 2; ++kb) {                                            \
        const int sidx = col16*64 + ((kgrp*8 + kb*32) ^ ((col16 & 7) << 3));    \
        ahA_hi[kb] = *(const short8*)(smem + O_HA_HI(CUR) + sidx);              \
        ahA_lo[kb] = *(const short8*)(smem + O_HA_LO(CUR) + sidx);              \
        ahB_hi[kb] = *(const short8*)(smem + O_HB_HI(CUR) + sidx);              \
        ahB_lo[kb] = *(const short8*)(smem + O_HB_LO(CUR) + sidx);              \
    }                                                                           \
    const short8 axA_hi = *(const short8*)(smem + O_XA_HI(CUR) + lane*8);       \
    const short8 axA_lo = *(const short8*)(smem + O_XA_LO(CUR) + lane*8);       \
    const short8 axB_hi = *(const short8*)(smem + O_XB_HI(CUR) + lane*8);       \
    const short8 axB_lo = *(const short8*)(smem + O_XB_LO(CUR) + lane*8);       \
    /* ---- store x(T+1) from regs prefetched one step ago ---- */              \
    if ((T) + 1 < T_) {                                                         \
        unsigned short h0,l0,h1,l1;                                             \
        split2(PXA_.x,h0,l0); split2(PXA_.y,h1,l1);                             \
        ((int*)(smem + O_XA_HI(nxt_)))[xii] = PACK2(h0,h1);                     \
        ((int*)(smem + O_XA_LO(nxt_)))[xii] = PACK2(l0,l1);                     \
        split2(PXB_.x,h0,l0); split2(PXB_.y,h1,l1);                             \
        ((int*)(smem + O_XB_HI(nxt_)))[xii] = PACK2(h0,h1);                     \
        ((int*)(smem + O_XB_LO(nxt_)))[xii] = PACK2(l0,l1);                     \
    }                                                                           \
    if ((T) + 2 < T_) {  /* issue loads for x(T+2) */                           \
        QXA_ = *(const float2*)(xsrcA + (size_t)((T)+2) * (N_*C_));             \
        QXB_ = *(const float2*)(xsrcB + (size_t)((T)+2) * (N_*C_));             \
    }                                                                           \
    /* ---- 8 acc chains (4 per tile), interleaved round-robin ---- */          \
    floatx4 aRA = {br,br,br,br},    aRB = {br,br,br,br};                        \
    floatx4 aZA = {bz,bz,bz,bz},    aZB = {bz,bz,bz,bz};                        \
    floatx4 aIA = {bin,bin,bin,bin},aIB = {bin,bin,bin,bin};                    \
    floatx4 aHA = {bhn,bhn,bhn,bhn},aHB = {bhn,bhn,bhn,bhn};                    \
    /* x round hh */                                                            \
    aRA = MFMA16(axA_hi, wih_hi[0], aRA);  aRB = MFMA16(axB_hi, wih_hi[0], aRB);\
    aZA = MFMA16(axA_hi, wih_hi[1], aZA);  aZB = MFMA16(axB_hi, wih_hi[1], aZB);\
    aIA = MFMA16(axA_hi, wih_hi[2], aIA);  aIB = MFMA16(axB_hi, wih_hi[2], aIB);\
    /* x round hl */                                                            \
    aRA = MFMA16(axA_hi, wih_lo[0], aRA);  aRB = MFMA16(axB_hi, wih_lo[0], aRB);\
    aZA = MFMA16(axA_hi, wih_lo[1], aZA);  aZB = MFMA16(axB_hi, wih_lo[1], aZB);\
    aIA = MFMA16(axA_hi, wih_lo[2], aIA);  aIB = MFMA16(axB_hi, wih_lo[2], aIB);\
    /* x round lh */                                                            \
    aRA = MFMA16(axA_lo, wih_hi[0], aRA);  aRB = MFMA16(axB_lo, wih_hi[0], aRB);\
    aZA = MFMA16(axA_lo, wih_hi[1], aZA);  aZB = MFMA16(axB_lo, wih_hi[1], aZB);\
    aIA = MFMA16(axA_lo, wih_hi[2], aIA);  aIB = MFMA16(axB_lo, wih_hi[2], aIB);\
    /* h kb0 rounds hh, hl, lh */                                               \
    aRA = MFMA16(ahA_hi[0], whh_hi[0][0], aRA); aRB = MFMA16(ahB_hi[0], whh_hi[0][0], aRB); \
    aZA = MFMA16(ahA_hi[0], whh_hi[1][0], aZA); aZB = MFMA16(ahB_hi[0], whh_hi[1][0], aZB); \
    aHA = MFMA16(ahA_hi[0], whh_hi[2][0], aHA); aHB = MFMA16(ahB_hi[0], whh_hi[2][0], aHB); \
    aRA = MFMA16(ahA_hi[0], whh_lo[0][0], aRA); aRB = MFMA16(ahB_hi[0], whh_lo[0][0], aRB); \
    aZA = MFMA16(ahA_hi[0], whh_lo[1][0], aZA); aZB = MFMA16(ahB_hi[0], whh_lo[1][0], aZB); \
    aHA = MFMA16(ahA_hi[0], whh_lo[2][0], aHA); aHB = MFMA16(ahB_hi[0], whh_lo[2][0], aHB); \
    aRA = MFMA16(ahA_lo[0], whh_hi[0][0], aRA); aRB = MFMA16(ahB_lo[0], whh_hi[0][0], aRB); \
    aZA = MFMA16(ahA_lo[0], whh_hi[1][0], aZA); aZB = MFMA16(ahB_lo[0], whh_hi[1][0], aZB); \
    aHA = MFMA16(ahA_lo[0], whh_hi[2][0], aHA); aHB = MFMA16(ahB_lo[0], whh_hi[2][0], aHB); \
    /* h kb1 rounds hh, hl, lh */                                               \
    aRA = MFMA16(ahA_hi[1], whh_hi[0][1], aRA); aRB = MFMA16(ahB_hi[1], whh_hi[0][1], aRB); \
    aZA = MFMA16(ahA_hi[1], whh_hi[1][1], aZA); aZB = MFMA16(ahB_hi[1], whh_hi[1][1], aZB); \
    aHA = MFMA16(ahA_hi[1], whh_hi[2][1], aHA); aHB = MFMA16(ahB_hi[1], whh_hi[2][1], aHB); \
    aRA = MFMA16(ahA_hi[1], whh_lo[0][1], aRA); aRB = MFMA16(ahB_hi[1], whh_lo[0][1], aRB); \
    aZA = MFMA16(ahA_hi[1], whh_lo[1][1], aZA); aZB = MFMA16(ahB_hi[1], whh_lo[1][1], aZB); \
    aHA = MFMA16(ahA_hi[1], whh_lo[2][1], aHA); aHB = MFMA16(ahB_hi[1], whh_lo[2][1], aHB); \
    aRA = MFMA16(ahA_lo[1], whh_hi[0][1], aRA); aRB = MFMA16(ahB_lo[1], whh_hi[0][1], aRB); \
    aZA = MFMA16(ahA_lo[1], whh_hi[1][1], aZA); aZB = MFMA16(ahB_lo[1], whh_hi[1][1], aZB); \
    aHA = MFMA16(ahA_lo[1], whh_hi[2][1], aHA); aHB = MFMA16(ahB_lo[1], whh_hi[2][1], aHB); \
    /* ---- activations + h store (both tiles) ---- */                          \
    short* nAh = smem + O_HA_HI(nxt_);  short* nAl = smem + O_HA_LO(nxt_);      \
    short* nBh = smem + O_HB_HI(nxt_);  short* nBl = smem + O_HB_LO(nxt_);      \
    _Pragma("unroll")                                                           \
    for (int s = 0; s < 4; ++s) {                                               \
        const int smp = kgrp*4 + s;                                             \
        const int idx = smp*64 + (jcol ^ ((smp & 7) << 3));                     \
        {                                                                       \
            const float r  = fsig(aRA[s]);                                      \
            const float z  = fsig(aZA[s]);                                      \
            const float nn = ftanh(aIA[s] + r * aHA[s]);                        \
            const float h  = (1.f - z) * nn + z * hpA[s];                       \
            hpA[s] = h;                                                         \
            unsigned short hh, hl; split2(h, hh, hl);                           \
            nAh[idx] = (short)hh;  nAl[idx] = (short)hl;                        \
        }                                                                       \
        {                                                                       \
            const float r  = fsig(aRB[s]);                                      \
            const float z  = fsig(aZB[s]);                                      \
            const float nn = ftanh(aIB[s] + r * aHB[s]);                        \
            const float h  = (1.f - z) * nn + z * hpB[s];                       \
            hpB[s] = h;                                                         \
            unsigned short hh, hl; split2(h, hh, hl);                           \
            nBh[idx] = (short)hh;  nBl[idx] = (short)hl;                        \
        }                                                                       \
    }                                                                           \
    BARRIER();                                                                  \
} while (0)

    for (int t = 0; t < T_; t += 2) {
        GRU_STEP(t,     0, pXA, pXB, qXA, qXB);
        GRU_STEP(t + 1, 1, qXA, qXB, pXA, pXB);
    }
#undef GRU_STEP

    // ---- write final hidden state (fp32 exact from registers) ----
    #pragma unroll
    for (int s = 0; s < 4; ++s) {
        const int smp = kgrp*4 + s;
        h_last[(size_t)(m0 + smp)*H_ + jcol]      = hpA[s];
        h_last[(size_t)(m0 + 16 + smp)*H_ + jcol] = hpB[s];
    }
}

// key/query projections: one wave per sample
__global__ __launch_bounds__(256) void kq_kernel(
    const float* __restrict__ h, const float* __restrict__ wk,
    const float* __restrict__ wq, float* __restrict__ key, float* __restrict__ query)
{
    int wave = (blockIdx.x * 256 + threadIdx.x) >> 6;
    int lane = threadIdx.x & 63;
    float hv = h[(size_t)wave * 64 + lane];
    float kv = hv * wk[lane];
    float qv = hv * wq[lane];
    #pragma unroll
    for (int off = 32; off; off >>= 1) {
        kv += __shfl_down(kv, off);
        qv += __shfl_down(qv, off);
    }
    if (lane == 0) { key[wave] = kv; query[wave] = qv; }
}

__global__ __launch_bounds__(256) void qmax_kernel(const float* __restrict__ query,
                                                   float* __restrict__ qmax)
{
    int b = blockIdx.x, tid = threadIdx.x;
    float m = -INFINITY;
    for (int i = tid; i < N_; i += 256) m = fmaxf(m, query[b*N_ + i]);
    #pragma unroll
    for (int off = 32; off; off >>= 1) m = fmaxf(m, __shfl_down(m, off));
    __shared__ float sm[4];
    if ((tid & 63) == 0) sm[tid >> 6] = m;
    __syncthreads();
    if (tid == 0) qmax[b] = fmaxf(fmaxf(sm[0], sm[1]), fmaxf(sm[2], sm[3]));
}

// softmax denominators: one wave per (b, row). Stores RECIPROCAL of the sum.
__global__ __launch_bounds__(256) void den_kernel(
    const float* __restrict__ key, const float* __restrict__ query,
    const float* __restrict__ qmax, float* __restrict__ den)
{
    int idx  = (blockIdx.x * 256 + threadIdx.x) >> 6;   // b*2048 + i
    int lane = threadIdx.x & 63;
    int b    = idx >> 11;
    float ki = key[idx];
    float mrow = lrelu(ki + qmax[b]);
    const float* q = query + ((size_t)b << 11);
    float sum = 0.f;
    for (int jj = lane; jj < N_; jj += 64)
        sum += __expf(lrelu(ki + q[jj]) - mrow);
    #pragma unroll
    for (int off = 32; off; off >>= 1) sum += __shfl_down(sum, off);
    if (lane == 0) den[idx] = 1.f / sum;    // reciprocal (sum >= 1 always)
}

// adj[i][j] = 0.125 * sum_b (attn[b][i][j] + attn[b][j][i]);  den holds 1/sum
__global__ __launch_bounds__(256) void out_kernel(
    const float* __restrict__ key, const float* __restrict__ query,
    const float* __restrict__ qmax, const float* __restrict__ den,
    float* __restrict__ out)
{
    int flat = blockIdx.x * 256 + threadIdx.x;
    int i = flat >> 11, j = flat & 2047;
    float acc = 0.f;
    #pragma unroll
    for (int b = 0; b < B_; ++b) {
        int bi = (b << 11) + i, bj = (b << 11) + j;
        float ki = key[bi], kj = key[bj];
        float qi = query[bi], qj = query[bj];
        float qm = qmax[b];
        float mi = lrelu(ki + qm), mj = lrelu(kj + qm);
        float aij = __expf(lrelu(ki + qj) - mi) * den[bi];
        float aji = __expf(lrelu(kj + qi) - mj) * den[bj];
        acc += aij + aji;
    }
    out[flat] = 0.125f * acc;
}

extern "C" void kernel_launch(void* const* d_in, const int* in_sizes, int n_in,
                              void* d_out, int out_size, void* d_ws, size_t ws_size,
                              hipStream_t stream) {
    const float* x    = (const float*)d_in[0];
    const float* w_ih = (const float*)d_in[1];
    const float* w_hh = (const float*)d_in[2];
    const float* b_ih = (const float*)d_in[3];
    const float* b_hh = (const float*)d_in[4];
    const float* wk   = (const float*)d_in[5];
    const float* wq   = (const float*)d_in[6];
    float* out = (float*)d_out;
    float* ws  = (float*)d_ws;

    // Bulk scratch (h_last, 2 MB) lives in d_out: dead before out_kernel
    // (the final launch) overwrites the entire 16 MB output.
    float* h_last = out;                      // [0, 524288) floats of d_out
    float* key    = ws;                       // 8192
    float* query  = ws + 8192;                // 8192
    float* qmax   = ws + 16384;               // 4
    float* den    = ws + 16388;               // 8192

    gru_kernel<<<M_/SPB, 256, 0, stream>>>(x, w_ih, w_hh, b_ih, b_hh, h_last);
    kq_kernel<<<M_/4, 256, 0, stream>>>(h_last, wk, wq, key, query);
    qmax_kernel<<<B_, 256, 0, stream>>>(query, qmax);
    den_kernel<<<M_/4, 256, 0, stream>>>(key, query, qmax, den);
    out_kernel<<<(N_*N_)/256, 256, 0, stream>>>(key, query, qmax, den, out);
}

// Round 8
// 117.411 us; speedup vs baseline: 1.1816x; 1.1816x over previous
//
#include <hip/hip_runtime.h>
#include <math.h>

#define B_ 4
#define T_ 64
#define N_ 2048
#define C_ 32
#define H_ 64
#define M_ (B_*N_)      // 8192
#define SLOPE 0.2f

typedef __attribute__((ext_vector_type(8))) short short8;   // 8 bf16 (4 VGPRs)
typedef __attribute__((ext_vector_type(4))) float floatx4;  // MFMA acc

#define MFMA16(a,b,c) __builtin_amdgcn_mfma_f32_16x16x32_bf16(a,b,c,0,0,0)

// Barrier without vmcnt drain: LDS visibility via lgkmcnt(0); global prefetch
// loads stay in flight. Uniform control flow at every use.
#define BARRIER() asm volatile("s_waitcnt lgkmcnt(0)\n\ts_barrier" ::: "memory")

__device__ __forceinline__ float lrelu(float v) { return v >= 0.f ? v : SLOPE * v; }
__device__ __forceinline__ float frcp(float x)  { return __builtin_amdgcn_rcpf(x); }
// sigmoid/tanh via v_exp + v_rcp (1-ulp rcp). Correct +-inf limits.
__device__ __forceinline__ float fsig(float x)  { return frcp(1.f + __expf(-x)); }
__device__ __forceinline__ float ftanh(float x) { return 1.f - 2.f * frcp(__expf(2.f * x) + 1.f); }

__device__ __forceinline__ unsigned short bf16_rtn(float f) {
    unsigned u = __float_as_uint(f);
    return (unsigned short)((u + 0x7fffu + ((u >> 16) & 1u)) >> 16);
}
__device__ __forceinline__ float bf16_f32(unsigned short s) {
    return __uint_as_float(((unsigned)s) << 16);
}
__device__ __forceinline__ void split2(float f, unsigned short& h, unsigned short& l) {
    h = bf16_rtn(f);
    l = bf16_rtn(f - bf16_f32(h));
}
// 8 fp32 -> bf16 hi/lo fragment pair
__device__ __forceinline__ void split8(float4 a, float4 b, short8& hi, short8& lo) {
    const float f[8] = {a.x,a.y,a.z,a.w,b.x,b.y,b.z,b.w};
    short8 h, l;
    #pragma unroll
    for (int e = 0; e < 8; ++e) {
        unsigned short hh, ll;
        split2(f[e], hh, ll);
        h[e] = (short)hh; l[e] = (short)ll;
    }
    hi = h; lo = l;
}

// 2 waves per block; wave wv owns gate-columns [wv*32, wv*32+32) of all 3 gates.
// h state: fp32 [16 rows][64 cols], double-buffered, XOR-swizzled col ^ ((row>>2)<<4)
// (write: 2 lanes/bank = free; read: contiguous 8-float b128 at per-lane addr).
__global__ __launch_bounds__(128, 1) void gru_kernel(
    const float* __restrict__ x,      // [B,T,N,C]
    const float* __restrict__ w_ih,   // [192][32]
    const float* __restrict__ w_hh,   // [192][64]
    const float* __restrict__ b_ih,   // [192]
    const float* __restrict__ b_hh,   // [192]
    float* __restrict__ h_last)       // [M][H]  (d_out scratch)
{
    __shared__ float hlds[2][16][64];   // 8 KB

    const int tid   = threadIdx.x;
    const int lane  = tid & 63;
    const int wv    = tid >> 6;        // wave 0..1
    const int col16 = lane & 15;
    const int kgrp  = lane >> 4;       // 0..3

    const int m0 = blockIdx.x * 16;
    const int b  = m0 >> 11;
    const int n0 = m0 & 2047;

    // ---- weight B-fragments -> registers (once). B[k][col] = w[col][k]. ----
    short8 whh_hi[3][2][2], whh_lo[3][2][2];   // [gate][tile i][kb]
    short8 wih_hi[3][2],    wih_lo[3][2];      // [gate][tile i]
    #pragma unroll
    for (int g = 0; g < 3; ++g) {
        #pragma unroll
        for (int i = 0; i < 2; ++i) {
            const int rw = g*64 + wv*32 + i*16 + col16;   // gate row
            #pragma unroll
            for (int kb = 0; kb < 2; ++kb) {
                const float* s = w_hh + rw*64 + kb*32 + kgrp*8;
                split8(*(const float4*)s, *(const float4*)(s+4),
                       whh_hi[g][i][kb], whh_lo[g][i][kb]);
            }
            const float* s2 = w_ih + rw*32 + kgrp*8;
            split8(*(const float4*)s2, *(const float4*)(s2+4),
                   wih_hi[g][i], wih_lo[g][i]);
        }
    }
    float br[2], bz[2], bin[2], bhn[2];
    #pragma unroll
    for (int i = 0; i < 2; ++i) {
        const int j = wv*32 + i*16 + col16;
        br[i]  = b_ih[j]      + b_hh[j];
        bz[i]  = b_ih[64+j]   + b_hh[64+j];
        bin[i] = b_ih[128+j];
        bhn[i] = b_hh[128+j];
    }

    // x A-frag source: row = col16 (sample), channels kgrp*8..+7 (2 float4/step)
    const float* xs = x + ((size_t)b*T_*N_ + (n0 + col16))*C_ + kgrp*8;
    const int xstride = N_*C_;

    for (int idx = tid; idx < 16*64; idx += 128)
        (&hlds[0][0][0])[idx] = 0.f;

    float4 cxa = *(const float4*)xs;                // x(0)
    float4 cxb = *(const float4*)(xs + 4);
    float4 pxa = *(const float4*)(xs + xstride);    // x(1) in flight
    float4 pxb = *(const float4*)(xs + xstride + 4);
    BARRIER();

    float hp[2][4] = {{0.f,0.f,0.f,0.f},{0.f,0.f,0.f,0.f}};

#define GRU_STEP(T, CUR, CXA_, CXB_) do {                                       \
    const int nxt_ = (CUR) ^ 1;                                                 \
    /* h A-frags: read 16 fp32, split to bf16 hi/lo in-reg */                   \
    short8 ah_hi[2], ah_lo[2];                                                  \
    _Pragma("unroll")                                                           \
    for (int kb = 0; kb < 2; ++kb) {                                            \
        const int cb = (kgrp*8 + kb*32) ^ ((col16 >> 2) << 4);                  \
        const float* hr = &hlds[CUR][col16][cb];                                \
        split8(*(const float4*)hr, *(const float4*)(hr+4),                      \
               ah_hi[kb], ah_lo[kb]);                                           \
    }                                                                           \
    short8 ax_hi, ax_lo;                                                        \
    split8(CXA_, CXB_, ax_hi, ax_lo);                                           \
    if ((T) + 2 < T_) {  /* reload consumed regs with x(T+2) */                 \
        CXA_ = *(const float4*)(xs + (size_t)((T)+2) * xstride);                \
        CXB_ = *(const float4*)(xs + (size_t)((T)+2) * xstride + 4);            \
    }                                                                           \
    floatx4 aR[2], aZ[2], aNI[2], aNH[2];                                       \
    _Pragma("unroll")                                                           \
    for (int i = 0; i < 2; ++i) {                                               \
        aR[i]  = (floatx4){br[i],br[i],br[i],br[i]};                            \
        aZ[i]  = (floatx4){bz[i],bz[i],bz[i],bz[i]};                            \
        aNI[i] = (floatx4){bin[i],bin[i],bin[i],bin[i]};                        \
        aNH[i] = (floatx4){bhn[i],bhn[i],bhn[i],bhn[i]};                        \
    }                                                                           \
    /* x projection: rounds hh, hl, lh over 6 independent chains */             \
    _Pragma("unroll")                                                           \
    for (int i = 0; i < 2; ++i) {                                               \
        aR[i]  = MFMA16(ax_hi, wih_hi[0][i], aR[i]);                            \
        aZ[i]  = MFMA16(ax_hi, wih_hi[1][i], aZ[i]);                            \
        aNI[i] = MFMA16(ax_hi, wih_hi[2][i], aNI[i]);                           \
    }                                                                           \
    _Pragma("unroll")                                                           \
    for (int i = 0; i < 2; ++i) {                                               \
        aR[i]  = MFMA16(ax_hi, wih_lo[0][i], aR[i]);                            \
        aZ[i]  = MFMA16(ax_hi, wih_lo[1][i], aZ[i]);                            \
        aNI[i] = MFMA16(ax_hi, wih_lo[2][i], aNI[i]);                           \
    }                                                                           \
    _Pragma("unroll")                                                           \
    for (int i = 0; i < 2; ++i) {                                               \
        aR[i]  = MFMA16(ax_lo, wih_hi[0][i], aR[i]);                            \
        aZ[i]  = MFMA16(ax_lo, wih_hi[1][i], aZ[i]);                            \
        aNI[i] = MFMA16(ax_lo, wih_hi[2][i], aNI[i]);                           \
    }                                                                           \
    /* h projection: kb = 0,1; rounds hh, hl, lh */                             \
    _Pragma("unroll")                                                           \
    for (int kb = 0; kb < 2; ++kb) {                                            \
        _Pragma("unroll")                                                       \
        for (int i = 0; i < 2; ++i) {                                           \
            aR[i]  = MFMA16(ah_hi[kb], whh_hi[0][i][kb], aR[i]);                \
            aZ[i]  = MFMA16(ah_hi[kb], whh_hi[1][i][kb], aZ[i]);                \
            aNH[i] = MFMA16(ah_hi[kb], whh_hi[2][i][kb], aNH[i]);               \
        }                                                                       \
        _Pragma("unroll")                                                       \
        for (int i = 0; i < 2; ++i) {                                           \
            aR[i]  = MFMA16(ah_hi[kb], whh_lo[0][i][kb], aR[i]);                \
            aZ[i]  = MFMA16(ah_hi[kb], whh_lo[1][i][kb], aZ[i]);                \
            aNH[i] = MFMA16(ah_hi[kb], whh_lo[2][i][kb], aNH[i]);               \
        }                                                                       \
        _Pragma("unroll")                                                       \
        for (int i = 0; i < 2; ++i) {                                           \
            aR[i]  = MFMA16(ah_lo[kb], whh_hi[0][i][kb], aR[i]);                \
            aZ[i]  = MFMA16(ah_lo[kb], whh_hi[1][i][kb], aZ[i]);                \
            aNH[i] = MFMA16(ah_lo[kb], whh_hi[2][i][kb], aNH[i]);               \
        }                                                                       \
    }                                                                           \
    /* activations (lane-local) + fp32 h store (swizzled) */                    \
    _Pragma("unroll")                                                           \
    for (int i = 0; i < 2; ++i) {                                               \
        _Pragma("unroll")                                                       \
        for (int s = 0; s < 4; ++s) {                                           \
            const float rr = fsig(aR[i][s]);                                    \
            const float zz = fsig(aZ[i][s]);                                    \
            const float nn = ftanh(aNI[i][s] + rr * aNH[i][s]);                 \
            const float h  = (1.f - zz) * nn + zz * hp[i][s];                   \
            hp[i][s] = h;                                                       \
            const int r = kgrp*4 + s;                                           \
            const int c = (wv*32 + i*16 + col16) ^ (kgrp << 4);                 \
            hlds[nxt_][r][c] = h;                                               \
        }                                                                       \
    }                                                                           \
    BARRIER();                                                                  \
} while (0)

    for (int t = 0; t < T_; t += 2) {
        GRU_STEP(t,     0, cxa, cxb);
        GRU_STEP(t + 1, 1, pxa, pxb);
    }
#undef GRU_STEP

    // ---- final hidden state from registers (fp32 exact) ----
    #pragma unroll
    for (int i = 0; i < 2; ++i)
        #pragma unroll
        for (int s = 0; s < 4; ++s)
            h_last[(size_t)(m0 + kgrp*4 + s)*H_ + wv*32 + i*16 + col16] = hp[i][s];
}

// key/query projections: one wave per sample
__global__ __launch_bounds__(256) void kq_kernel(
    const float* __restrict__ h, const float* __restrict__ wk,
    const float* __restrict__ wq, float* __restrict__ key, float* __restrict__ query)
{
    int wave = (blockIdx.x * 256 + threadIdx.x) >> 6;
    int lane = threadIdx.x & 63;
    float hv = h[(size_t)wave * 64 + lane];
    float kv = hv * wk[lane];
    float qv = hv * wq[lane];
    #pragma unroll
    for (int off = 32; off; off >>= 1) {
        kv += __shfl_down(kv, off);
        qv += __shfl_down(qv, off);
    }
    if (lane == 0) { key[wave] = kv; query[wave] = qv; }
}

__global__ __launch_bounds__(256) void qmax_kernel(const float* __restrict__ query,
                                                   float* __restrict__ qmax)
{
    int b = blockIdx.x, tid = threadIdx.x;
    float m = -INFINITY;
    for (int i = tid; i < N_; i += 256) m = fmaxf(m, query[b*N_ + i]);
    #pragma unroll
    for (int off = 32; off; off >>= 1) m = fmaxf(m, __shfl_down(m, off));
    __shared__ float sm[4];
    if ((tid & 63) == 0) sm[tid >> 6] = m;
    __syncthreads();
    if (tid == 0) qmax[b] = fmaxf(fmaxf(sm[0], sm[1]), fmaxf(sm[2], sm[3]));
}

// softmax denominators: one wave per (b, row). Stores RECIPROCAL of the sum.
__global__ __launch_bounds__(256) void den_kernel(
    const float* __restrict__ key, const float* __restrict__ query,
    const float* __restrict__ qmax, float* __restrict__ den)
{
    int idx  = (blockIdx.x * 256 + threadIdx.x) >> 6;   // b*2048 + i
    int lane = threadIdx.x & 63;
    int b    = idx >> 11;
    float ki = key[idx];
    float mrow = lrelu(ki + qmax[b]);
    const float* q = query + ((size_t)b << 11);
    float sum = 0.f;
    for (int jj = lane; jj < N_; jj += 64)
        sum += __expf(lrelu(ki + q[jj]) - mrow);
    #pragma unroll
    for (int off = 32; off; off >>= 1) sum += __shfl_down(sum, off);
    if (lane == 0) den[idx] = 1.f / sum;    // reciprocal (sum >= 1 always)
}

// adj[i][j] = 0.125 * sum_b (attn[b][i][j] + attn[b][j][i]);  den holds 1/sum
__global__ __launch_bounds__(256) void out_kernel(
    const float* __restrict__ key, const float* __restrict__ query,
    const float* __restrict__ qmax, const float* __restrict__ den,
    float* __restrict__ out)
{
    int flat = blockIdx.x * 256 + threadIdx.x;
    int i = flat >> 11, j = flat & 2047;
    float acc = 0.f;
    #pragma unroll
    for (int b = 0; b < B_; ++b) {
        int bi = (b << 11) + i, bj = (b << 11) + j;
        float ki = key[bi], kj = key[bj];
        float qi = query[bi], qj = query[bj];
        float qm = qmax[b];
        float mi = lrelu(ki + qm), mj = lrelu(kj + qm);
        float aij = __expf(lrelu(ki + qj) - mi) * den[bi];
        float aji = __expf(lrelu(kj + qi) - mj) * den[bj];
        acc += aij + aji;
    }
    out[flat] = 0.125f * acc;
}

extern "C" void kernel_launch(void* const* d_in, const int* in_sizes, int n_in,
                              void* d_out, int out_size, void* d_ws, size_t ws_size,
                              hipStream_t stream) {
    const float* x    = (const float*)d_in[0];
    const float* w_ih = (const float*)d_in[1];
    const float* w_hh = (const float*)d_in[2];
    const float* b_ih = (const float*)d_in[3];
    const float* b_hh = (const float*)d_in[4];
    const float* wk   = (const float*)d_in[5];
    const float* wq   = (const float*)d_in[6];
    float* out = (float*)d_out;
    float* ws  = (float*)d_ws;

    // Bulk scratch (h_last, 2 MB) lives in d_out: dead before out_kernel
    // (the final launch) overwrites the entire 16 MB output.
    float* h_last = out;                      // [0, 524288) floats of d_out
    float* key    = ws;                       // 8192
    float* query  = ws + 8192;                // 8192
    float* qmax   = ws + 16384;               // 4
    float* den    = ws + 16388;               // 8192

    gru_kernel<<<M_/16, 128, 0, stream>>>(x, w_ih, w_hh, b_ih, b_hh, h_last);
    kq_kernel<<<M_/4, 256, 0, stream>>>(h_last, wk, wq, key, query);
    qmax_kernel<<<B_, 256, 0, stream>>>(query, qmax);
    den_kernel<<<M_/4, 256, 0, stream>>>(key, query, qmax, den);
    out_kernel<<<(N_*N_)/256, 256, 0, stream>>>(key, query, qmax, den, out);
}

// Round 9
// 103.093 us; speedup vs baseline: 1.3457x; 1.1389x over previous
//
#include <hip/hip_runtime.h>
#include <hip/hip_bf16.h>
#include <math.h>

#define B_ 4
#define T_ 64
#define N_ 2048
#define C_ 32
#define H_ 64
#define M_ (B_*N_)      // 8192
#define SLOPE 0.2f
#define LOG2E 1.44269504088896340736f

typedef __attribute__((ext_vector_type(8))) short short8;   // 8 bf16 (4 VGPRs)
typedef __attribute__((ext_vector_type(4))) float floatx4;  // MFMA acc

#define MFMA16(a,b,c) __builtin_amdgcn_mfma_f32_16x16x32_bf16(a,b,c,0,0,0)

// Barrier without vmcnt drain: LDS visibility via lgkmcnt(0); global prefetch
// loads stay in flight. Uniform control flow at every use.
#define BARRIER() asm volatile("s_waitcnt lgkmcnt(0)\n\ts_barrier" ::: "memory")

__device__ __forceinline__ float lrelu(float v) { return fmaxf(v, SLOPE * v); }
__device__ __forceinline__ float frcp(float x)  { return __builtin_amdgcn_rcpf(x); }
__device__ __forceinline__ float fexp2(float x) { float r; asm("v_exp_f32 %0, %1" : "=v"(r) : "v"(x)); return r; }

__device__ __forceinline__ unsigned short f2bf(float f) {
    union { __hip_bfloat16 b; unsigned short u; } cv;
    cv.b = __float2bfloat16(f);          // HW cvt; lo term compensates rounding
    return cv.u;
}
__device__ __forceinline__ float bf16_f32(unsigned short s) {
    return __uint_as_float(((unsigned)s) << 16);
}
// 8 fp32 (scaled) -> bf16 hi/lo fragment pair
__device__ __forceinline__ void split8s(const float* f, float sc, short8& hi, short8& lo) {
    short8 h, l;
    #pragma unroll
    for (int e = 0; e < 8; ++e) {
        const float v = f[e] * sc;
        const unsigned short hh = f2bf(v);
        const unsigned short ll = f2bf(v - bf16_f32(hh));
        h[e] = (short)hh; l[e] = (short)ll;
    }
    hi = h; lo = l;
}
__device__ __forceinline__ void split8v(float4 a, float4 b, short8& hi, short8& lo) {
    const float f[8] = {a.x,a.y,a.z,a.w,b.x,b.y,b.z,b.w};
    short8 h, l;
    #pragma unroll
    for (int e = 0; e < 8; ++e) {
        const unsigned short hh = f2bf(f[e]);
        const unsigned short ll = f2bf(f[e] - bf16_f32(hh));
        h[e] = (short)hh; l[e] = (short)ll;
    }
    hi = h; lo = l;
}

// 2 waves/block; wave wv owns gate-cols [wv*32, wv*32+32).
// h state in LDS as PRE-SPLIT bf16 hi/lo arrays [16 samples][64 dims],
// double-buffered; element-swizzle c ^ ((r>>2)<<4) (write conflict-free,
// read contiguous b128). Split cost paid ONCE at write (8 vals/thread).
__global__ __launch_bounds__(128, 1) void gru_kernel(
    const float* __restrict__ x,      // [B,T,N,C]
    const float* __restrict__ w_ih,   // [192][32]
    const float* __restrict__ w_hh,   // [192][64]
    const float* __restrict__ b_ih,   // [192]
    const float* __restrict__ b_hh,   // [192]
    float* __restrict__ h_last)       // [M][H]  (d_out scratch)
{
    __shared__ __align__(16) short hhi[2][16][64];   // 4 KB
    __shared__ __align__(16) short hlo[2][16][64];   // 4 KB

    const int tid   = threadIdx.x;
    const int lane  = tid & 63;
    const int wv    = tid >> 6;        // wave 0..1
    const int col16 = lane & 15;
    const int kgrp  = lane >> 4;       // 0..3

    const int m0 = blockIdx.x * 16;
    const int b  = m0 >> 11;
    const int n0 = m0 & 2047;

    // Gate scales folded into weights/biases:
    //   r: -log2e  (r = rcp(1+exp2(aR)))
    //   z: +log2e  (1-z = rcp(1+exp2(aZ)))
    //   n: 2*log2e (tanh = 1-2*rcp(1+exp2(v)))
    const float gsc[3] = {-LOG2E, LOG2E, 2.f*LOG2E};

    short8 whh_hi[3][2][2], whh_lo[3][2][2];   // [gate][col tile i][kb]
    short8 wih_hi[3][2],    wih_lo[3][2];
    #pragma unroll
    for (int g = 0; g < 3; ++g) {
        #pragma unroll
        for (int i = 0; i < 2; ++i) {
            const int rw = g*64 + wv*32 + i*16 + col16;
            #pragma unroll
            for (int kb = 0; kb < 2; ++kb)
                split8s(w_hh + rw*64 + kb*32 + kgrp*8, gsc[g],
                        whh_hi[g][i][kb], whh_lo[g][i][kb]);
            split8s(w_ih + rw*32 + kgrp*8, gsc[g], wih_hi[g][i], wih_lo[g][i]);
        }
    }
    float br[2], bz[2], bin[2], bhn[2];
    #pragma unroll
    for (int i = 0; i < 2; ++i) {
        const int j = wv*32 + i*16 + col16;
        br[i]  = -LOG2E     * (b_ih[j]    + b_hh[j]);
        bz[i]  =  LOG2E     * (b_ih[64+j] + b_hh[64+j]);
        bin[i] =  2.f*LOG2E * b_ih[128+j];
        bhn[i] =  2.f*LOG2E * b_hh[128+j];
    }

    // x A-frag source: sample row = col16, channels kgrp*8..+7
    const float* xs = x + ((size_t)b*T_*N_ + (n0 + col16))*C_ + kgrp*8;
    const int xstride = N_*C_;

    for (int idx = tid; idx < 16*64/2; idx += 128) {   // zero buf0 (hi+lo)
        ((int*)&hhi[0][0][0])[idx] = 0;
        ((int*)&hlo[0][0][0])[idx] = 0;
    }

    float4 cxa = *(const float4*)xs;                // x(0)
    float4 cxb = *(const float4*)(xs + 4);
    float4 pxa = *(const float4*)(xs + xstride);    // x(1) in flight
    float4 pxb = *(const float4*)(xs + xstride + 4);
    BARRIER();

    float hp[2][4] = {{0.f,0.f,0.f,0.f},{0.f,0.f,0.f,0.f}};

#define GRU_STEP(T, CUR, CXA_, CXB_) do {                                       \
    const int nxt_ = (CUR) ^ 1;                                                 \
    /* h A-frags: direct bf16 reads, no conversion */                           \
    short8 ah_hi[2], ah_lo[2];                                                  \
    _Pragma("unroll")                                                           \
    for (int kb = 0; kb < 2; ++kb) {                                            \
        const int ke = (kgrp*8 + kb*32) ^ ((col16 >> 2) << 4);                  \
        ah_hi[kb] = *(const short8*)&hhi[CUR][col16][ke];                       \
        ah_lo[kb] = *(const short8*)&hlo[CUR][col16][ke];                       \
    }                                                                           \
    short8 ax_hi, ax_lo;                                                        \
    split8v(CXA_, CXB_, ax_hi, ax_lo);                                          \
    if ((T) + 2 < T_) {  /* reload consumed regs with x(T+2) */                 \
        CXA_ = *(const float4*)(xs + (size_t)((T)+2) * xstride);                \
        CXB_ = *(const float4*)(xs + (size_t)((T)+2) * xstride + 4);            \
    }                                                                           \
    floatx4 aR[2], aZ[2], aNI[2], aNH[2];                                       \
    _Pragma("unroll")                                                           \
    for (int i = 0; i < 2; ++i) {                                               \
        aR[i]  = (floatx4){br[i],br[i],br[i],br[i]};                            \
        aZ[i]  = (floatx4){bz[i],bz[i],bz[i],bz[i]};                            \
        aNI[i] = (floatx4){bin[i],bin[i],bin[i],bin[i]};                        \
        aNH[i] = (floatx4){bhn[i],bhn[i],bhn[i],bhn[i]};                        \
    }                                                                           \
    _Pragma("unroll")                                                           \
    for (int i = 0; i < 2; ++i) {                                               \
        aR[i]  = MFMA16(ax_hi, wih_hi[0][i], aR[i]);                            \
        aZ[i]  = MFMA16(ax_hi, wih_hi[1][i], aZ[i]);                            \
        aNI[i] = MFMA16(ax_hi, wih_hi[2][i], aNI[i]);                           \
    }                                                                           \
    _Pragma("unroll")                                                           \
    for (int i = 0; i < 2; ++i) {                                               \
        aR[i]  = MFMA16(ax_hi, wih_lo[0][i], aR[i]);                            \
        aZ[i]  = MFMA16(ax_hi, wih_lo[1][i], aZ[i]);                            \
        aNI[i] = MFMA16(ax_hi, wih_lo[2][i], aNI[i]);                           \
    }                                                                           \
    _Pragma("unroll")                                                           \
    for (int i = 0; i < 2; ++i) {                                               \
        aR[i]  = MFMA16(ax_lo, wih_hi[0][i], aR[i]);                            \
        aZ[i]  = MFMA16(ax_lo, wih_hi[1][i], aZ[i]);                            \
        aNI[i] = MFMA16(ax_lo, wih_hi[2][i], aNI[i]);                           \
    }                                                                           \
    _Pragma("unroll")                                                           \
    for (int kb = 0; kb < 2; ++kb) {                                            \
        _Pragma("unroll")                                                       \
        for (int i = 0; i < 2; ++i) {                                           \
            aR[i]  = MFMA16(ah_hi[kb], whh_hi[0][i][kb], aR[i]);                \
            aZ[i]  = MFMA16(ah_hi[kb], whh_hi[1][i][kb], aZ[i]);                \
            aNH[i] = MFMA16(ah_hi[kb], whh_hi[2][i][kb], aNH[i]);               \
        }                                                                       \
        _Pragma("unroll")                                                       \
        for (int i = 0; i < 2; ++i) {                                           \
            aR[i]  = MFMA16(ah_hi[kb], whh_lo[0][i][kb], aR[i]);                \
            aZ[i]  = MFMA16(ah_hi[kb], whh_lo[1][i][kb], aZ[i]);                \
            aNH[i] = MFMA16(ah_hi[kb], whh_lo[2][i][kb], aNH[i]);               \
        }                                                                       \
        _Pragma("unroll")                                                       \
        for (int i = 0; i < 2; ++i) {                                           \
            aR[i]  = MFMA16(ah_lo[kb], whh_hi[0][i][kb], aR[i]);                \
            aZ[i]  = MFMA16(ah_lo[kb], whh_hi[1][i][kb], aZ[i]);                \
            aNH[i] = MFMA16(ah_lo[kb], whh_hi[2][i][kb], aNH[i]);               \
        }                                                                       \
    }                                                                           \
    /* activations: exp2-native, no muls; split h once at write */              \
    _Pragma("unroll")                                                           \
    for (int i = 0; i < 2; ++i) {                                               \
        _Pragma("unroll")                                                       \
        for (int s = 0; s < 4; ++s) {                                           \
            const float tr = frcp(1.f + fexp2(aR[i][s]));      /* = r   */      \
            const float v  = fmaf(tr, aNH[i][s], aNI[i][s]);                    \
            const float tn = frcp(1.f + fexp2(v));                              \
            const float nn = fmaf(tn, -2.f, 1.f);              /* tanh */       \
            const float tw = frcp(1.f + fexp2(aZ[i][s]));      /* = 1-z */      \
            const float h  = fmaf(tw, nn - hp[i][s], hp[i][s]);                 \
            hp[i][s] = h;                                                       \
            const unsigned short hh = f2bf(h);                                  \
            const unsigned short hl = f2bf(h - bf16_f32(hh));                   \
            const int r = kgrp*4 + s;                                           \
            const int c = (wv*32 + i*16 + col16) ^ (kgrp << 4);                 \
            hhi[nxt_][r][c] = (short)hh;                                        \
            hlo[nxt_][r][c] = (short)hl;                                        \
        }                                                                       \
    }                                                                           \
    BARRIER();                                                                  \
} while (0)

    for (int t = 0; t < T_; t += 2) {
        GRU_STEP(t,     0, cxa, cxb);
        GRU_STEP(t + 1, 1, pxa, pxb);
    }
#undef GRU_STEP

    // ---- final hidden state from registers (fp32 exact) ----
    #pragma unroll
    for (int i = 0; i < 2; ++i)
        #pragma unroll
        for (int s = 0; s < 4; ++s)
            h_last[(size_t)(m0 + kgrp*4 + s)*H_ + wv*32 + i*16 + col16] = hp[i][s];
}

// key/query projections, PRE-SCALED by log2e: one wave per sample
__global__ __launch_bounds__(256) void kq_kernel(
    const float* __restrict__ h, const float* __restrict__ wk,
    const float* __restrict__ wq, float* __restrict__ key, float* __restrict__ query)
{
    int wave = (blockIdx.x * 256 + threadIdx.x) >> 6;
    int lane = threadIdx.x & 63;
    float hv = h[(size_t)wave * 64 + lane];
    float kv = hv * wk[lane];
    float qv = hv * wq[lane];
    #pragma unroll
    for (int off = 32; off; off >>= 1) {
        kv += __shfl_down(kv, off);
        qv += __shfl_down(qv, off);
    }
    if (lane == 0) { key[wave] = kv * LOG2E; query[wave] = qv * LOG2E; }
}

__global__ __launch_bounds__(256) void qmax_kernel(const float* __restrict__ query,
                                                   float* __restrict__ qmax)
{
    int b = blockIdx.x, tid = threadIdx.x;
    float m = -INFINITY;
    for (int i = tid; i < N_; i += 256) m = fmaxf(m, query[b*N_ + i]);
    #pragma unroll
    for (int off = 32; off; off >>= 1) m = fmaxf(m, __shfl_down(m, off));
    __shared__ float sm[4];
    if ((tid & 63) == 0) sm[tid >> 6] = m;
    __syncthreads();
    if (tid == 0) qmax[b] = fmaxf(fmaxf(sm[0], sm[1]), fmaxf(sm[2], sm[3]));
}

// den stores Di = rcp(sum) * exp2(-m)  so attn_ij = exp2(lrelu(ki+qj)) * Di.
// (key/query are log2e-scaled; |scores| small so exp2(lrelu(.)) cannot overflow)
__global__ __launch_bounds__(256) void den_kernel(
    const float* __restrict__ key, const float* __restrict__ query,
    const float* __restrict__ qmax, float* __restrict__ den)
{
    int idx  = (blockIdx.x * 256 + threadIdx.x) >> 6;   // b*2048 + i
    int lane = threadIdx.x & 63;
    int b    = idx >> 11;
    float ki = key[idx];
    float m2 = lrelu(ki + qmax[b]);
    const float4* q4 = (const float4*)(query + ((size_t)b << 11));
    float sum = 0.f;
    for (int jj = lane; jj < N_/4; jj += 64) {
        float4 qv = q4[jj];
        sum += fexp2(lrelu(ki + qv.x) - m2) + fexp2(lrelu(ki + qv.y) - m2)
             + fexp2(lrelu(ki + qv.z) - m2) + fexp2(lrelu(ki + qv.w) - m2);
    }
    #pragma unroll
    for (int off = 32; off; off >>= 1) sum += __shfl_down(sum, off);
    if (lane == 0) den[idx] = frcp(sum) * fexp2(-m2);
}

// adj[i][j] = 0.125 * sum_b (attn[b][i][j] + attn[b][j][i])
__global__ __launch_bounds__(256) void out_kernel(
    const float* __restrict__ key, const float* __restrict__ query,
    const float* __restrict__ den, float* __restrict__ out)
{
    int flat = blockIdx.x * 256 + threadIdx.x;
    int i = flat >> 11, j = flat & 2047;
    float acc = 0.f;
    #pragma unroll
    for (int b = 0; b < B_; ++b) {
        int bi = (b << 11) + i, bj = (b << 11) + j;
        float e1 = fexp2(lrelu(key[bi] + query[bj]));
        float e2 = fexp2(lrelu(key[bj] + query[bi]));
        acc = fmaf(e1, den[bi], acc);
        acc = fmaf(e2, den[bj], acc);
    }
    out[flat] = 0.125f * acc;
}

extern "C" void kernel_launch(void* const* d_in, const int* in_sizes, int n_in,
                              void* d_out, int out_size, void* d_ws, size_t ws_size,
                              hipStream_t stream) {
    const float* x    = (const float*)d_in[0];
    const float* w_ih = (const float*)d_in[1];
    const float* w_hh = (const float*)d_in[2];
    const float* b_ih = (const float*)d_in[3];
    const float* b_hh = (const float*)d_in[4];
    const float* wk   = (const float*)d_in[5];
    const float* wq   = (const float*)d_in[6];
    float* out = (float*)d_out;
    float* ws  = (float*)d_ws;

    // Bulk scratch (h_last, 2 MB) lives in d_out: dead before out_kernel
    // (the final launch) overwrites the entire 16 MB output.
    float* h_last = out;                      // [0, 524288) floats of d_out
    float* key    = ws;                       // 8192
    float* query  = ws + 8192;                // 8192
    float* qmax   = ws + 16384;               // 4
    float* den    = ws + 16388;               // 8192

    gru_kernel<<<M_/16, 128, 0, stream>>>(x, w_ih, w_hh, b_ih, b_hh, h_last);
    kq_kernel<<<M_/4, 256, 0, stream>>>(h_last, wk, wq, key, query);
    qmax_kernel<<<B_, 256, 0, stream>>>(query, qmax);
    den_kernel<<<M_/4, 256, 0, stream>>>(key, query, qmax, den);
    out_kernel<<<(N_*N_)/256, 256, 0, stream>>>(key, query, den, out);
}

// Round 10
// 101.027 us; speedup vs baseline: 1.3732x; 1.0204x over previous
//
#include <hip/hip_runtime.h>
#include <hip/hip_bf16.h>
#include <math.h>

#define B_ 4
#define T_ 64
#define N_ 2048
#define C_ 32
#define H_ 64
#define M_ (B_*N_)      // 8192
#define SLOPE 0.2f
#define LOG2E 1.44269504088896340736f

typedef __attribute__((ext_vector_type(8))) short short8;   // 8 bf16 (4 VGPRs)
typedef __attribute__((ext_vector_type(4))) float floatx4;  // MFMA acc

#define MFMA16(a,b,c) __builtin_amdgcn_mfma_f32_16x16x32_bf16(a,b,c,0,0,0)

// Barrier without vmcnt drain: LDS visibility via lgkmcnt(0); global prefetch
// loads stay in flight. Uniform control flow at every use.
#define BARRIER() asm volatile("s_waitcnt lgkmcnt(0)\n\ts_barrier" ::: "memory")

__device__ __forceinline__ float lrelu(float v) { return fmaxf(v, SLOPE * v); }
__device__ __forceinline__ float frcp(float x)  { return __builtin_amdgcn_rcpf(x); }
__device__ __forceinline__ float fexp2(float x) { float r; asm("v_exp_f32 %0, %1" : "=v"(r) : "v"(x)); return r; }

__device__ __forceinline__ unsigned short f2bf(float f) {
    union { __hip_bfloat16 b; unsigned short u; } cv;
    cv.b = __float2bfloat16(f);          // HW cvt; lo term compensates rounding
    return cv.u;
}
__device__ __forceinline__ float bf16_f32(unsigned short s) {
    return __uint_as_float(((unsigned)s) << 16);
}
// 8 fp32 (scaled) -> bf16 hi/lo fragment pair (weights, setup only)
__device__ __forceinline__ void split8s(const float* f, float sc, short8& hi, short8& lo) {
    short8 h, l;
    #pragma unroll
    for (int e = 0; e < 8; ++e) {
        const float v = f[e] * sc;
        const unsigned short hh = f2bf(v);
        const unsigned short ll = f2bf(v - bf16_f32(hh));
        h[e] = (short)hh; l[e] = (short)ll;
    }
    hi = h; lo = l;
}
#define PACK2(h0,h1) ((int)(unsigned)(h0) | ((int)(h1) << 16))

// ---------------- GRU kernel ----------------
// 512 blocks x 256 threads (4 waves) = 2 blocks/CU = 2 waves/SIMD.
// Block owns 16 samples; wave w owns gate-cols [w*16, w*16+16) of r,z,n.
// h state: pre-split bf16 hi/lo in LDS [2][16][64], col-swizzle c^((r>>2)<<4).
// x tile: pre-split bf16 hi/lo in LDS [2][16][32], cooperative staging
// (1 float2/thread/step), block-swizzled for read: int idx = row*16 +
// ((kblk ^ (row&3))*4 + off). Write 2-way free; read ~4-way on 2 b128.
__global__ __launch_bounds__(256, 2) void gru_kernel(
    const float* __restrict__ x,      // [B,T,N,C]
    const float* __restrict__ w_ih,   // [192][32]
    const float* __restrict__ w_hh,   // [192][64]
    const float* __restrict__ b_ih,   // [192]
    const float* __restrict__ b_hh,   // [192]
    float* __restrict__ h_last)       // [M][H]  (d_out scratch)
{
    __shared__ __align__(16) short hhi[2][16][64];   // 4 KB
    __shared__ __align__(16) short hlo[2][16][64];   // 4 KB
    __shared__ __align__(16) short xhi[2][16][32];   // 2 KB
    __shared__ __align__(16) short xlo[2][16][32];   // 2 KB

    const int tid   = threadIdx.x;
    const int lane  = tid & 63;
    const int w     = tid >> 6;        // wave 0..3
    const int col16 = lane & 15;
    const int kgrp  = lane >> 4;       // 0..3

    const int m0 = blockIdx.x * 16;
    const int b  = m0 >> 11;
    const int n0 = m0 & 2047;

    // Gate scales folded into weights/biases:
    //  r: -log2e (r = rcp(1+exp2(aR))); z: +log2e (1-z = rcp(1+exp2(aZ)));
    //  n: 2*log2e (tanh(v) = 1-2*rcp(1+exp2(2*log2e*v)))
    const float gsc[3] = {-LOG2E, LOG2E, 2.f*LOG2E};

    // Weight B-fragments (this wave's 16 cols of each gate): B[k][col]=w[col][k]
    short8 whhH[3][2], whhL[3][2];   // [gate][kb]
    short8 wihH[3],    wihL[3];
    #pragma unroll
    for (int g = 0; g < 3; ++g) {
        const int rw = g*64 + w*16 + col16;
        #pragma unroll
        for (int kb = 0; kb < 2; ++kb)
            split8s(w_hh + rw*64 + kb*32 + kgrp*8, gsc[g], whhH[g][kb], whhL[g][kb]);
        split8s(w_ih + rw*32 + kgrp*8, gsc[g], wihH[g], wihL[g]);
    }
    const int jcol = w*16 + col16;
    const float br  = -LOG2E     * (b_ih[jcol]    + b_hh[jcol]);
    const float bz  =  LOG2E     * (b_ih[64+jcol] + b_hh[64+jcol]);
    const float bin =  2.f*LOG2E * b_ih[128+jcol];
    const float bhn =  2.f*LOG2E * b_hh[128+jcol];
    const floatx4 bR4  = {br, br, br, br};     // persistent: C-operand of first
    const floatx4 bZ4  = {bz, bz, bz, bz};     // MFMA of each chain = free init
    const floatx4 bNI4 = {bin, bin, bin, bin};
    const floatx4 bNH4 = {bhn, bhn, bhn, bhn};
    const floatx4 zero4 = {0.f, 0.f, 0.f, 0.f};

    // x staging geometry: thread covers sample row xr, channels 2*xq, 2*xq+1
    const int xr = tid >> 4;           // 0..15
    const int xq = tid & 15;           // 0..15
    const int xkblk = xq >> 2, xoff = xq & 3;
    const int xwi = xr*16 + ((xkblk ^ (xr & 3))*4 + xoff);   // int index in x-buf
    const float* xsrc = x + ((size_t)b*T_*N_ + (n0 + xr))*C_ + 2*xq;
    const int xstride = N_*C_;

    // zero h buf0
    for (int idx = tid; idx < 16*64/2; idx += 256) {
        ((int*)&hhi[0][0][0])[idx] = 0;
        ((int*)&hlo[0][0][0])[idx] = 0;
    }
    // stage x(0) into buf0
    {
        const float v0 = xsrc[0], v1 = xsrc[1];
        const unsigned short h0 = f2bf(v0), h1 = f2bf(v1);
        const unsigned short l0 = f2bf(v0 - bf16_f32(h0)), l1 = f2bf(v1 - bf16_f32(h1));
        ((int*)&xhi[0][0][0])[xwi] = PACK2(h0, h1);
        ((int*)&xlo[0][0][0])[xwi] = PACK2(l0, l1);
    }
    float2 pxa = *(const float2*)(xsrc + xstride);    // x(1) in flight
    float2 pxb = {0.f, 0.f};
    BARRIER();

    float hp[4] = {0.f, 0.f, 0.f, 0.f};

#define GRU_STEP(T, CUR, PX_, QX_) do {                                         \
    const int nxt_ = (CUR) ^ 1;                                                 \
    /* h A-frags (shared across waves): 4 ds_read_b128, pre-split */            \
    short8 ah_hi[2], ah_lo[2];                                                  \
    _Pragma("unroll")                                                           \
    for (int kb = 0; kb < 2; ++kb) {                                            \
        const int ke = (kgrp*8 + kb*32) ^ ((col16 >> 2) << 4);                  \
        ah_hi[kb] = *(const short8*)&hhi[CUR][col16][ke];                       \
        ah_lo[kb] = *(const short8*)&hlo[CUR][col16][ke];                       \
    }                                                                           \
    /* x A-frag: 2 ds_read_b128 (swizzled block) */                             \
    const int xre = ((kgrp ^ (col16 & 3))*4) << 1;   /* short offset */         \
    const short8 ax_hi = *(const short8*)&xhi[CUR][col16][xre];                 \
    const short8 ax_lo = *(const short8*)&xlo[CUR][col16][xre];                 \
    /* stage x(T+1) into NXT from regs loaded one step ago */                   \
    if ((T) + 1 < T_) {                                                         \
        const unsigned short h0 = f2bf(PX_.x), h1 = f2bf(PX_.y);                \
        const unsigned short l0 = f2bf(PX_.x - bf16_f32(h0));                   \
        const unsigned short l1 = f2bf(PX_.y - bf16_f32(h1));                   \
        ((int*)&xhi[nxt_][0][0])[xwi] = PACK2(h0, h1);                          \
        ((int*)&xlo[nxt_][0][0])[xwi] = PACK2(l0, l1);                          \
    }                                                                           \
    if ((T) + 2 < T_) {  /* issue load x(T+2) */                                \
        QX_ = *(const float2*)(xsrc + (size_t)((T)+2) * xstride);               \
    }                                                                           \
    /* x-phase: 3 chains (Rx,Zx,NI), bias as C of first MFMA */                 \
    floatx4 aRx = MFMA16(ax_hi, wihH[0], bR4);                                  \
    floatx4 aZx = MFMA16(ax_hi, wihH[1], bZ4);                                  \
    floatx4 aNI = MFMA16(ax_hi, wihH[2], bNI4);                                 \
    aRx = MFMA16(ax_hi, wihL[0], aRx);                                          \
    aZx = MFMA16(ax_hi, wihL[1], aZx);                                          \
    aNI = MFMA16(ax_hi, wihL[2], aNI);                                          \
    aRx = MFMA16(ax_lo, wihH[0], aRx);                                          \
    aZx = MFMA16(ax_lo, wihH[1], aZx);                                          \
    aNI = MFMA16(ax_lo, wihH[2], aNI);                                          \
    /* h-phase: 6 chains (per-kb split) -> dependent spacing 6 */               \
    floatx4 aRh0 = MFMA16(ah_hi[0], whhH[0][0], zero4);                         \
    floatx4 aZh0 = MFMA16(ah_hi[0], whhH[1][0], zero4);                         \
    floatx4 aNH0 = MFMA16(ah_hi[0], whhH[2][0], bNH4);                          \
    floatx4 aRh1 = MFMA16(ah_hi[1], whhH[0][1], zero4);                         \
    floatx4 aZh1 = MFMA16(ah_hi[1], whhH[1][1], zero4);                         \
    floatx4 aNH1 = MFMA16(ah_hi[1], whhH[2][1], zero4);                         \
    aRh0 = MFMA16(ah_hi[0], whhL[0][0], aRh0);                                  \
    aZh0 = MFMA16(ah_hi[0], whhL[1][0], aZh0);                                  \
    aNH0 = MFMA16(ah_hi[0], whhL[2][0], aNH0);                                  \
    aRh1 = MFMA16(ah_hi[1], whhL[0][1], aRh1);                                  \
    aZh1 = MFMA16(ah_hi[1], whhL[1][1], aZh1);                                  \
    aNH1 = MFMA16(ah_hi[1], whhL[2][1], aNH1);                                  \
    aRh0 = MFMA16(ah_lo[0], whhH[0][0], aRh0);                                  \
    aZh0 = MFMA16(ah_lo[0], whhH[1][0], aZh0);                                  \
    aNH0 = MFMA16(ah_lo[0], whhH[2][0], aNH0);                                  \
    aRh1 = MFMA16(ah_lo[1], whhH[0][1], aRh1);                                  \
    aZh1 = MFMA16(ah_lo[1], whhH[1][1], aZh1);                                  \
    aNH1 = MFMA16(ah_lo[1], whhH[2][1], aNH1);                                  \
    /* activations (lane-local, exp2-native) + pre-split h store */             \
    _Pragma("unroll")                                                           \
    for (int s = 0; s < 4; ++s) {                                               \
        const float rs = aRx[s] + aRh0[s] + aRh1[s];                            \
        const float zs = aZx[s] + aZh0[s] + aZh1[s];                            \
        const float nh = aNH0[s] + aNH1[s];                                     \
        const float tr = frcp(1.f + fexp2(rs));          /* = r   */            \
        const float v  = fmaf(tr, nh, aNI[s]);                                  \
        const float tn = frcp(1.f + fexp2(v));                                  \
        const float nn = fmaf(tn, -2.f, 1.f);            /* tanh */             \
        const float tw = frcp(1.f + fexp2(zs));          /* = 1-z */            \
        const float h  = fmaf(tw, nn - hp[s], hp[s]);                           \
        hp[s] = h;                                                              \
        const unsigned short hh = f2bf(h);                                      \
        const unsigned short hl = f2bf(h - bf16_f32(hh));                       \
        const int r = kgrp*4 + s;                                               \
        const int c = jcol ^ (kgrp << 4);                                       \
        hhi[nxt_][r][c] = (short)hh;                                            \
        hlo[nxt_][r][c] = (short)hl;                                            \
    }                                                                           \
    BARRIER();                                                                  \
} while (0)

    for (int t = 0; t < T_; t += 2) {
        GRU_STEP(t,     0, pxa, pxb);
        GRU_STEP(t + 1, 1, pxb, pxa);
    }
#undef GRU_STEP

    // final hidden state from registers (fp32 exact)
    #pragma unroll
    for (int s = 0; s < 4; ++s)
        h_last[(size_t)(m0 + kgrp*4 + s)*H_ + jcol] = hp[s];
}

// key/query projections, PRE-SCALED by log2e: one wave per sample
__global__ __launch_bounds__(256) void kq_kernel(
    const float* __restrict__ h, const float* __restrict__ wk,
    const float* __restrict__ wq, float* __restrict__ key, float* __restrict__ query)
{
    int wave = (blockIdx.x * 256 + threadIdx.x) >> 6;
    int lane = threadIdx.x & 63;
    float hv = h[(size_t)wave * 64 + lane];
    float kv = hv * wk[lane];
    float qv = hv * wq[lane];
    #pragma unroll
    for (int off = 32; off; off >>= 1) {
        kv += __shfl_down(kv, off);
        qv += __shfl_down(qv, off);
    }
    if (lane == 0) { key[wave] = kv * LOG2E; query[wave] = qv * LOG2E; }
}

__global__ __launch_bounds__(256) void qmax_kernel(const float* __restrict__ query,
                                                   float* __restrict__ qmax)
{
    int b = blockIdx.x, tid = threadIdx.x;
    float m = -INFINITY;
    for (int i = tid; i < N_; i += 256) m = fmaxf(m, query[b*N_ + i]);
    #pragma unroll
    for (int off = 32; off; off >>= 1) m = fmaxf(m, __shfl_down(m, off));
    __shared__ float sm[4];
    if ((tid & 63) == 0) sm[tid >> 6] = m;
    __syncthreads();
    if (tid == 0) qmax[b] = fmaxf(fmaxf(sm[0], sm[1]), fmaxf(sm[2], sm[3]));
}

// den stores Di = rcp(sum) * exp2(-m)  so attn_ij = exp2(lrelu(ki+qj)) * Di.
__global__ __launch_bounds__(256) void den_kernel(
    const float* __restrict__ key, const float* __restrict__ query,
    const float* __restrict__ qmax, float* __restrict__ den)
{
    int idx  = (blockIdx.x * 256 + threadIdx.x) >> 6;   // b*2048 + i
    int lane = threadIdx.x & 63;
    int b    = idx >> 11;
    float ki = key[idx];
    float m2 = lrelu(ki + qmax[b]);
    const float4* q4 = (const float4*)(query + ((size_t)b << 11));
    float sum = 0.f;
    for (int jj = lane; jj < N_/4; jj += 64) {
        float4 qv = q4[jj];
        sum += fexp2(lrelu(ki + qv.x) - m2) + fexp2(lrelu(ki + qv.y) - m2)
             + fexp2(lrelu(ki + qv.z) - m2) + fexp2(lrelu(ki + qv.w) - m2);
    }
    #pragma unroll
    for (int off = 32; off; off >>= 1) sum += __shfl_down(sum, off);
    if (lane == 0) den[idx] = frcp(sum) * fexp2(-m2);
}

// adj[i][j] = 0.125 * sum_b (attn[b][i][j] + attn[b][j][i])
__global__ __launch_bounds__(256) void out_kernel(
    const float* __restrict__ key, const float* __restrict__ query,
    const float* __restrict__ den, float* __restrict__ out)
{
    int flat = blockIdx.x * 256 + threadIdx.x;
    int i = flat >> 11, j = flat & 2047;
    float acc = 0.f;
    #pragma unroll
    for (int b = 0; b < B_; ++b) {
        int bi = (b << 11) + i, bj = (b << 11) + j;
        float e1 = fexp2(lrelu(key[bi] + query[bj]));
        float e2 = fexp2(lrelu(key[bj] + query[bi]));
        acc = fmaf(e1, den[bi], acc);
        acc = fmaf(e2, den[bj], acc);
    }
    out[flat] = 0.125f * acc;
}

extern "C" void kernel_launch(void* const* d_in, const int* in_sizes, int n_in,
                              void* d_out, int out_size, void* d_ws, size_t ws_size,
                              hipStream_t stream) {
    const float* x    = (const float*)d_in[0];
    const float* w_ih = (const float*)d_in[1];
    const float* w_hh = (const float*)d_in[2];
    const float* b_ih = (const float*)d_in[3];
    const float* b_hh = (const float*)d_in[4];
    const float* wk   = (const float*)d_in[5];
    const float* wq   = (const float*)d_in[6];
    float* out = (float*)d_out;
    float* ws  = (float*)d_ws;

    // Bulk scratch (h_last, 2 MB) lives in d_out: dead before out_kernel
    // (the final launch) overwrites the entire 16 MB output.
    float* h_last = out;                      // [0, 524288) floats of d_out
    float* key    = ws;                       // 8192
    float* query  = ws + 8192;                // 8192
    float* qmax   = ws + 16384;               // 4
    float* den    = ws + 16388;               // 8192

    gru_kernel<<<M_/16, 256, 0, stream>>>(x, w_ih, w_hh, b_ih, b_hh, h_last);
    kq_kernel<<<M_/4, 256, 0, stream>>>(h_last, wk, wq, key, query);
    qmax_kernel<<<B_, 256, 0, stream>>>(query, qmax);
    den_kernel<<<M_/4, 256, 0, stream>>>(key, query, qmax, den);
    out_kernel<<<(N_*N_)/256, 256, 0, stream>>>(key, query, den, out);
}

// Round 11
// 88.384 us; speedup vs baseline: 1.5697x; 1.1431x over previous
//
#include <hip/hip_runtime.h>
#include <hip/hip_bf16.h>
#include <math.h>

#define B_ 4
#define T_ 64
#define N_ 2048
#define C_ 32
#define H_ 64
#define M_ (B_*N_)      // 8192
#define SLOPE 0.2f
#define LOG2E 1.44269504088896340736f

typedef __attribute__((ext_vector_type(8))) short short8;   // 8 bf16 (4 VGPRs)
typedef __attribute__((ext_vector_type(4))) float floatx4;  // MFMA acc

#define MFMA16(a,b,c) __builtin_amdgcn_mfma_f32_16x16x32_bf16(a,b,c,0,0,0)

// Barrier without vmcnt drain: LDS visibility via lgkmcnt(0); global prefetch
// loads stay in flight. Uniform control flow at every use.
#define BARRIER() asm volatile("s_waitcnt lgkmcnt(0)\n\ts_barrier" ::: "memory")

__device__ __forceinline__ float lrelu(float v) { return fmaxf(v, SLOPE * v); }
__device__ __forceinline__ float frcp(float x)  { return __builtin_amdgcn_rcpf(x); }
__device__ __forceinline__ float fexp2(float x) { float r; asm("v_exp_f32 %0, %1" : "=v"(r) : "v"(x)); return r; }

__device__ __forceinline__ unsigned short f2bf(float f) {
    union { __hip_bfloat16 b; unsigned short u; } cv;
    cv.b = __float2bfloat16(f);          // HW cvt; lo term compensates rounding
    return cv.u;
}
__device__ __forceinline__ float bf16_f32(unsigned short s) {
    return __uint_as_float(((unsigned)s) << 16);
}
// 8 fp32 (scaled) -> bf16 hi/lo fragment pair (weights, setup only)
__device__ __forceinline__ void split8s(const float* f, float sc, short8& hi, short8& lo) {
    short8 h, l;
    #pragma unroll
    for (int e = 0; e < 8; ++e) {
        const float v = f[e] * sc;
        const unsigned short hh = f2bf(v);
        const unsigned short ll = f2bf(v - bf16_f32(hh));
        h[e] = (short)hh; l[e] = (short)ll;
    }
    hi = h; lo = l;
}
#define PACK2(h0,h1) ((int)(unsigned)(h0) | ((int)(h1) << 16))

// ---------------- GRU kernel (with fused key/query projection) ----------------
// 512 blocks x 256 threads (4 waves) = 2 blocks/CU = 2 waves/SIMD.
// Block owns 16 samples; wave w owns gate-cols [w*16, w*16+16) of r,z,n.
// h state: pre-split bf16 hi/lo in LDS [2][16][64], col-swizzle c^((r>>2)<<4).
// x tile: pre-split bf16 hi/lo in LDS [2][16][32], cooperative staging.
// Epilogue: k/q projections reduced in-wave (shfl_xor) + cross-wave (LDS);
// h never touches global memory.
__global__ __launch_bounds__(256, 2) void gru_kernel(
    const float* __restrict__ x,      // [B,T,N,C]
    const float* __restrict__ w_ih,   // [192][32]
    const float* __restrict__ w_hh,   // [192][64]
    const float* __restrict__ b_ih,   // [192]
    const float* __restrict__ b_hh,   // [192]
    const float* __restrict__ wk_p,   // [64]
    const float* __restrict__ wq_p,   // [64]
    float* __restrict__ key,          // [M]  (log2e-scaled)
    float* __restrict__ query)        // [M]  (log2e-scaled)
{
    __shared__ __align__(16) short hhi[2][16][64];   // 4 KB
    __shared__ __align__(16) short hlo[2][16][64];   // 4 KB
    __shared__ __align__(16) short xhi[2][16][32];   // 2 KB
    __shared__ __align__(16) short xlo[2][16][32];   // 2 KB
    __shared__ float kq_lds[2][16][4];               // [k/q][sample][wave]

    const int tid   = threadIdx.x;
    const int lane  = tid & 63;
    const int w     = tid >> 6;        // wave 0..3
    const int col16 = lane & 15;
    const int kgrp  = lane >> 4;       // 0..3

    const int m0 = blockIdx.x * 16;
    const int b  = m0 >> 11;
    const int n0 = m0 & 2047;

    // Gate scales folded into weights/biases:
    //  r: -log2e (r = rcp(1+exp2(aR))); z: +log2e (1-z = rcp(1+exp2(aZ)));
    //  n: 2*log2e (tanh(v) = 1-2*rcp(1+exp2(2*log2e*v)))
    const float gsc[3] = {-LOG2E, LOG2E, 2.f*LOG2E};

    // Weight B-fragments (this wave's 16 cols of each gate): B[k][col]=w[col][k]
    short8 whhH[3][2], whhL[3][2];   // [gate][kb]
    short8 wihH[3],    wihL[3];
    #pragma unroll
    for (int g = 0; g < 3; ++g) {
        const int rw = g*64 + w*16 + col16;
        #pragma unroll
        for (int kb = 0; kb < 2; ++kb)
            split8s(w_hh + rw*64 + kb*32 + kgrp*8, gsc[g], whhH[g][kb], whhL[g][kb]);
        split8s(w_ih + rw*32 + kgrp*8, gsc[g], wihH[g], wihL[g]);
    }
    const int jcol = w*16 + col16;
    const float br  = -LOG2E     * (b_ih[jcol]    + b_hh[jcol]);
    const float bz  =  LOG2E     * (b_ih[64+jcol] + b_hh[64+jcol]);
    const float bin =  2.f*LOG2E * b_ih[128+jcol];
    const float bhn =  2.f*LOG2E * b_hh[128+jcol];
    const floatx4 bR4  = {br, br, br, br};     // persistent: C-operand of first
    const floatx4 bZ4  = {bz, bz, bz, bz};     // MFMA of each chain = free init
    const floatx4 bNI4 = {bin, bin, bin, bin};
    const floatx4 bNH4 = {bhn, bhn, bhn, bhn};
    const floatx4 zero4 = {0.f, 0.f, 0.f, 0.f};

    const float wkj = wk_p[jcol] * LOG2E;      // fused kq projection weights
    const float wqj = wq_p[jcol] * LOG2E;

    // x staging geometry: thread covers sample row xr, channels 2*xq, 2*xq+1
    const int xr = tid >> 4;           // 0..15
    const int xq = tid & 15;           // 0..15
    const int xkblk = xq >> 2, xoff = xq & 3;
    const int xwi = xr*16 + ((xkblk ^ (xr & 3))*4 + xoff);   // int index in x-buf
    const float* xsrc = x + ((size_t)b*T_*N_ + (n0 + xr))*C_ + 2*xq;
    const int xstride = N_*C_;

    // zero h buf0
    for (int idx = tid; idx < 16*64/2; idx += 256) {
        ((int*)&hhi[0][0][0])[idx] = 0;
        ((int*)&hlo[0][0][0])[idx] = 0;
    }
    // stage x(0) into buf0
    {
        const float v0 = xsrc[0], v1 = xsrc[1];
        const unsigned short h0 = f2bf(v0), h1 = f2bf(v1);
        const unsigned short l0 = f2bf(v0 - bf16_f32(h0)), l1 = f2bf(v1 - bf16_f32(h1));
        ((int*)&xhi[0][0][0])[xwi] = PACK2(h0, h1);
        ((int*)&xlo[0][0][0])[xwi] = PACK2(l0, l1);
    }
    float2 pxa = *(const float2*)(xsrc + xstride);    // x(1) in flight
    float2 pxb = {0.f, 0.f};
    BARRIER();

    float hp[4] = {0.f, 0.f, 0.f, 0.f};

#define GRU_STEP(T, CUR, PX_, QX_) do {                                         \
    const int nxt_ = (CUR) ^ 1;                                                 \
    /* h A-frags (shared across waves): 4 ds_read_b128, pre-split */            \
    short8 ah_hi[2], ah_lo[2];                                                  \
    _Pragma("unroll")                                                           \
    for (int kb = 0; kb < 2; ++kb) {                                            \
        const int ke = (kgrp*8 + kb*32) ^ ((col16 >> 2) << 4);                  \
        ah_hi[kb] = *(const short8*)&hhi[CUR][col16][ke];                       \
        ah_lo[kb] = *(const short8*)&hlo[CUR][col16][ke];                       \
    }                                                                           \
    /* x A-frag: 2 ds_read_b128 (swizzled block) */                             \
    const int xre = ((kgrp ^ (col16 & 3))*4) << 1;   /* short offset */         \
    const short8 ax_hi = *(const short8*)&xhi[CUR][col16][xre];                 \
    const short8 ax_lo = *(const short8*)&xlo[CUR][col16][xre];                 \
    /* stage x(T+1) into NXT from regs loaded one step ago */                   \
    if ((T) + 1 < T_) {                                                         \
        const unsigned short h0 = f2bf(PX_.x), h1 = f2bf(PX_.y);                \
        const unsigned short l0 = f2bf(PX_.x - bf16_f32(h0));                   \
        const unsigned short l1 = f2bf(PX_.y - bf16_f32(h1));                   \
        ((int*)&xhi[nxt_][0][0])[xwi] = PACK2(h0, h1);                          \
        ((int*)&xlo[nxt_][0][0])[xwi] = PACK2(l0, l1);                          \
    }                                                                           \
    if ((T) + 2 < T_) {  /* issue load x(T+2) */                                \
        QX_ = *(const float2*)(xsrc + (size_t)((T)+2) * xstride);               \
    }                                                                           \
    /* x-phase: 3 chains (Rx,Zx,NI), bias as C of first MFMA */                 \
    floatx4 aRx = MFMA16(ax_hi, wihH[0], bR4);                                  \
    floatx4 aZx = MFMA16(ax_hi, wihH[1], bZ4);                                  \
    floatx4 aNI = MFMA16(ax_hi, wihH[2], bNI4);                                 \
    aRx = MFMA16(ax_hi, wihL[0], aRx);                                          \
    aZx = MFMA16(ax_hi, wihL[1], aZx);                                          \
    aNI = MFMA16(ax_hi, wihL[2], aNI);                                          \
    aRx = MFMA16(ax_lo, wihH[0], aRx);                                          \
    aZx = MFMA16(ax_lo, wihH[1], aZx);                                          \
    aNI = MFMA16(ax_lo, wihH[2], aNI);                                          \
    /* h-phase: 6 chains (per-kb split) -> dependent spacing 6 */               \
    floatx4 aRh0 = MFMA16(ah_hi[0], whhH[0][0], zero4);                         \
    floatx4 aZh0 = MFMA16(ah_hi[0], whhH[1][0], zero4);                         \
    floatx4 aNH0 = MFMA16(ah_hi[0], whhH[2][0], bNH4);                          \
    floatx4 aRh1 = MFMA16(ah_hi[1], whhH[0][1], zero4);                         \
    floatx4 aZh1 = MFMA16(ah_hi[1], whhH[1][1], zero4);                         \
    floatx4 aNH1 = MFMA16(ah_hi[1], whhH[2][1], zero4);                         \
    aRh0 = MFMA16(ah_hi[0], whhL[0][0], aRh0);                                  \
    aZh0 = MFMA16(ah_hi[0], whhL[1][0], aZh0);                                  \
    aNH0 = MFMA16(ah_hi[0], whhL[2][0], aNH0);                                  \
    aRh1 = MFMA16(ah_hi[1], whhL[0][1], aRh1);                                  \
    aZh1 = MFMA16(ah_hi[1], whhL[1][1], aZh1);                                  \
    aNH1 = MFMA16(ah_hi[1], whhL[2][1], aNH1);                                  \
    aRh0 = MFMA16(ah_lo[0], whhH[0][0], aRh0);                                  \
    aZh0 = MFMA16(ah_lo[0], whhH[1][0], aZh0);                                  \
    aNH0 = MFMA16(ah_lo[0], whhH[2][0], aNH0);                                  \
    aRh1 = MFMA16(ah_lo[1], whhH[0][1], aRh1);                                  \
    aZh1 = MFMA16(ah_lo[1], whhH[1][1], aZh1);                                  \
    aNH1 = MFMA16(ah_lo[1], whhH[2][1], aNH1);                                  \
    /* activations (lane-local, exp2-native) + pre-split h store */             \
    _Pragma("unroll")                                                           \
    for (int s = 0; s < 4; ++s) {                                               \
        const float rs = aRx[s] + aRh0[s] + aRh1[s];                            \
        const float zs = aZx[s] + aZh0[s] + aZh1[s];                            \
        const float nh = aNH0[s] + aNH1[s];                                     \
        const float tr = frcp(1.f + fexp2(rs));          /* = r   */            \
        const float v  = fmaf(tr, nh, aNI[s]);                                  \
        const float tn = frcp(1.f + fexp2(v));                                  \
        const float nn = fmaf(tn, -2.f, 1.f);            /* tanh */             \
        const float tw = frcp(1.f + fexp2(zs));          /* = 1-z */            \
        const float h  = fmaf(tw, nn - hp[s], hp[s]);                           \
        hp[s] = h;                                                              \
        const unsigned short hh = f2bf(h);                                      \
        const unsigned short hl = f2bf(h - bf16_f32(hh));                       \
        const int r = kgrp*4 + s;                                               \
        const int c = jcol ^ (kgrp << 4);                                       \
        hhi[nxt_][r][c] = (short)hh;                                            \
        hlo[nxt_][r][c] = (short)hl;                                            \
    }                                                                           \
    BARRIER();                                                                  \
} while (0)

    for (int t = 0; t < T_; t += 2) {
        GRU_STEP(t,     0, pxa, pxb);
        GRU_STEP(t + 1, 1, pxb, pxa);
    }
#undef GRU_STEP

    // ---- fused key/query projection epilogue ----
    // per-lane partials over its single col, 4 samples
    float kp[4], qp[4];
    #pragma unroll
    for (int s = 0; s < 4; ++s) { kp[s] = hp[s] * wkj; qp[s] = hp[s] * wqj; }
    // reduce over the 16 lanes of this kgrp group (xor masks 1,2,4,8)
    #pragma unroll
    for (int mask = 8; mask; mask >>= 1) {
        #pragma unroll
        for (int s = 0; s < 4; ++s) {
            kp[s] += __shfl_xor(kp[s], mask);
            qp[s] += __shfl_xor(qp[s], mask);
        }
    }
    if (col16 == 0) {
        #pragma unroll
        for (int s = 0; s < 4; ++s) {
            kq_lds[0][kgrp*4 + s][w] = kp[s];
            kq_lds[1][kgrp*4 + s][w] = qp[s];
        }
    }
    __syncthreads();
    if (tid < 32) {
        const int smp = tid & 15, sel = tid >> 4;
        const float v = kq_lds[sel][smp][0] + kq_lds[sel][smp][1]
                      + kq_lds[sel][smp][2] + kq_lds[sel][smp][3];
        (sel ? query : key)[m0 + smp] = v;
    }
}

// den stores rcp(sum_j exp2(lrelu(ki+qj))).  No max-shift needed: |scores| are
// small (|k|,|q| <~ 2 typ., <20 worst-case) -> exp2 args far inside fp32 range.
__global__ __launch_bounds__(256) void den_kernel(
    const float* __restrict__ key, const float* __restrict__ query,
    float* __restrict__ den)
{
    int idx  = (blockIdx.x * 256 + threadIdx.x) >> 6;   // b*2048 + i
    int lane = threadIdx.x & 63;
    int b    = idx >> 11;
    float ki = key[idx];
    const float4* q4 = (const float4*)(query + ((size_t)b << 11));
    float sum = 0.f;
    for (int jj = lane; jj < N_/4; jj += 64) {
        float4 qv = q4[jj];
        sum += fexp2(lrelu(ki + qv.x)) + fexp2(lrelu(ki + qv.y))
             + fexp2(lrelu(ki + qv.z)) + fexp2(lrelu(ki + qv.w));
    }
    #pragma unroll
    for (int off = 32; off; off >>= 1) sum += __shfl_down(sum, off);
    if (lane == 0) den[idx] = frcp(sum);
}

// adj[i][j] = 0.125 * sum_b (attn[b][i][j] + attn[b][j][i]); float4 over j
__global__ __launch_bounds__(256) void out_kernel(
    const float* __restrict__ key, const float* __restrict__ query,
    const float* __restrict__ den, float* __restrict__ out)
{
    const int flat = blockIdx.x * 256 + threadIdx.x;   // N*N/4 float4 elems
    const int i  = flat >> 9;            // row (wave-uniform within block)
    const int j0 = (flat & 511) << 2;    // first of 4 cols
    float4 acc = {0.f, 0.f, 0.f, 0.f};
    #pragma unroll
    for (int b = 0; b < B_; ++b) {
        const int bi = (b << 11) + i, bj = (b << 11) + j0;
        const float ki = key[bi], qi = query[bi], di = den[bi];
        const float4 k4 = *(const float4*)&key[bj];
        const float4 q4 = *(const float4*)&query[bj];
        const float4 d4 = *(const float4*)&den[bj];
        acc.x = fmaf(fexp2(lrelu(ki + q4.x)), di, acc.x);
        acc.y = fmaf(fexp2(lrelu(ki + q4.y)), di, acc.y);
        acc.z = fmaf(fexp2(lrelu(ki + q4.z)), di, acc.z);
        acc.w = fmaf(fexp2(lrelu(ki + q4.w)), di, acc.w);
        acc.x = fmaf(fexp2(lrelu(k4.x + qi)), d4.x, acc.x);
        acc.y = fmaf(fexp2(lrelu(k4.y + qi)), d4.y, acc.y);
        acc.z = fmaf(fexp2(lrelu(k4.z + qi)), d4.z, acc.z);
        acc.w = fmaf(fexp2(lrelu(k4.w + qi)), d4.w, acc.w);
    }
    acc.x *= 0.125f; acc.y *= 0.125f; acc.z *= 0.125f; acc.w *= 0.125f;
    ((float4*)out)[flat] = acc;
}

extern "C" void kernel_launch(void* const* d_in, const int* in_sizes, int n_in,
                              void* d_out, int out_size, void* d_ws, size_t ws_size,
                              hipStream_t stream) {
    const float* x    = (const float*)d_in[0];
    const float* w_ih = (const float*)d_in[1];
    const float* w_hh = (const float*)d_in[2];
    const float* b_ih = (const float*)d_in[3];
    const float* b_hh = (const float*)d_in[4];
    const float* wk   = (const float*)d_in[5];
    const float* wq   = (const float*)d_in[6];
    float* out = (float*)d_out;
    float* ws  = (float*)d_ws;

    float* key   = ws;             // 8192
    float* query = ws + 8192;      // 8192
    float* den   = ws + 16384;     // 8192

    gru_kernel<<<M_/16, 256, 0, stream>>>(x, w_ih, w_hh, b_ih, b_hh,
                                          wk, wq, key, query);
    den_kernel<<<M_/4, 256, 0, stream>>>(key, query, den);
    out_kernel<<<(N_*N_/4)/256, 256, 0, stream>>>(key, query, den, out);
}

// Round 12
// 82.765 us; speedup vs baseline: 1.6762x; 1.0679x over previous
//
#include <hip/hip_runtime.h>
#include <hip/hip_bf16.h>
#include <math.h>

#define B_ 4
#define T_ 64
#define N_ 2048
#define C_ 32
#define H_ 64
#define M_ (B_*N_)      // 8192
#define SLOPE 0.2f
#define LOG2E 1.44269504088896340736f

typedef __attribute__((ext_vector_type(8))) short short8;   // 8 bf16 (4 VGPRs)
typedef __attribute__((ext_vector_type(4))) float floatx4;  // MFMA acc

#define MFMA16(a,b,c) __builtin_amdgcn_mfma_f32_16x16x32_bf16(a,b,c,0,0,0)

// Barrier without vmcnt drain: LDS visibility via lgkmcnt(0); global prefetch
// loads stay in flight. Uniform control flow at every use.
#define BARRIER() asm volatile("s_waitcnt lgkmcnt(0)\n\ts_barrier" ::: "memory")

__device__ __forceinline__ float lrelu(float v) { return fmaxf(v, SLOPE * v); }
__device__ __forceinline__ float frcp(float x)  { return __builtin_amdgcn_rcpf(x); }
__device__ __forceinline__ float fexp2(float x) { float r; asm("v_exp_f32 %0, %1" : "=v"(r) : "v"(x)); return r; }

__device__ __forceinline__ unsigned short f2bf(float f) {
    union { __hip_bfloat16 b; unsigned short u; } cv;
    cv.b = __float2bfloat16(f);          // HW cvt; lo term compensates rounding
    return cv.u;
}
__device__ __forceinline__ float bf16_f32(unsigned short s) {
    return __uint_as_float(((unsigned)s) << 16);
}
// 8 fp32 (scaled) -> bf16 hi/lo fragment pair
__device__ __forceinline__ void split8s(const float* f, float sc, short8& hi, short8& lo) {
    short8 h, l;
    #pragma unroll
    for (int e = 0; e < 8; ++e) {
        const float v = f[e] * sc;
        const unsigned short hh = f2bf(v);
        const unsigned short ll = f2bf(v - bf16_f32(hh));
        h[e] = (short)hh; l[e] = (short)ll;
    }
    hi = h; lo = l;
}
__device__ __forceinline__ void split8v(float4 a, float4 b, short8& hi, short8& lo) {
    const float f[8] = {a.x,a.y,a.z,a.w,b.x,b.y,b.z,b.w};
    short8 h, l;
    #pragma unroll
    for (int e = 0; e < 8; ++e) {
        const unsigned short hh = f2bf(f[e]);
        const unsigned short ll = f2bf(f[e] - bf16_f32(hh));
        h[e] = (short)hh; l[e] = (short)ll;
    }
    hi = h; lo = l;
}

// ---------------- GRU kernel (fused kq; x fully in registers) ----------------
// 512 blocks x 256 threads (4 waves) = 2 blocks/CU = 2 waves/SIMD.
// Block owns 16 samples; wave w owns gate-cols [w*16, w*16+16) of r,z,n.
// h state: pre-split bf16 hi/lo in LDS [2][16][64], col-swizzle c^((r>>2)<<4).
// x: NO LDS. Each lane loads its own A-frag rows direct from global (2-step
// prefetch); step t+1's x-phase MFMAs are issued at the END of region t so
// they overlap act(t), the barrier wait, and region t+1's h ds_read latency.
__global__ __launch_bounds__(256, 2) void gru_kernel(
    const float* __restrict__ x,      // [B,T,N,C]
    const float* __restrict__ w_ih,   // [192][32]
    const float* __restrict__ w_hh,   // [192][64]
    const float* __restrict__ b_ih,   // [192]
    const float* __restrict__ b_hh,   // [192]
    const float* __restrict__ wk_p,   // [64]
    const float* __restrict__ wq_p,   // [64]
    float* __restrict__ key,          // [M]  (log2e-scaled)
    float* __restrict__ query)        // [M]  (log2e-scaled)
{
    __shared__ __align__(16) short hhi[2][16][64];   // 4 KB
    __shared__ __align__(16) short hlo[2][16][64];   // 4 KB
    __shared__ float kq_lds[2][16][4];               // [k/q][sample][wave]

    const int tid   = threadIdx.x;
    const int lane  = tid & 63;
    const int w     = tid >> 6;        // wave 0..3
    const int col16 = lane & 15;
    const int kgrp  = lane >> 4;       // 0..3

    const int m0 = blockIdx.x * 16;
    const int b  = m0 >> 11;
    const int n0 = m0 & 2047;

    // Gate scales folded into weights/biases:
    //  r: -log2e (r = rcp(1+exp2(aR))); z: +log2e (1-z = rcp(1+exp2(aZ)));
    //  n: 2*log2e (tanh(v) = 1-2*rcp(1+exp2(2*log2e*v)))
    const float gsc[3] = {-LOG2E, LOG2E, 2.f*LOG2E};

    // Weight B-fragments (this wave's 16 cols of each gate): B[k][col]=w[col][k]
    short8 whhH[3][2], whhL[3][2];   // [gate][kb]
    short8 wihH[3],    wihL[3];
    #pragma unroll
    for (int g = 0; g < 3; ++g) {
        const int rw = g*64 + w*16 + col16;
        #pragma unroll
        for (int kb = 0; kb < 2; ++kb)
            split8s(w_hh + rw*64 + kb*32 + kgrp*8, gsc[g], whhH[g][kb], whhL[g][kb]);
        split8s(w_ih + rw*32 + kgrp*8, gsc[g], wihH[g], wihL[g]);
    }
    const int jcol = w*16 + col16;
    const float br  = -LOG2E     * (b_ih[jcol]    + b_hh[jcol]);
    const float bz  =  LOG2E     * (b_ih[64+jcol] + b_hh[64+jcol]);
    const float bin =  2.f*LOG2E * b_ih[128+jcol];
    const float bhn =  2.f*LOG2E * b_hh[128+jcol];
    const floatx4 bR4  = {br, br, br, br};     // persistent C-operand seeds
    const floatx4 bZ4  = {bz, bz, bz, bz};
    const floatx4 bNI4 = {bin, bin, bin, bin};
    const floatx4 bNH4 = {bhn, bhn, bhn, bhn};
    const floatx4 zero4 = {0.f, 0.f, 0.f, 0.f};

    const float wkj = wk_p[jcol] * LOG2E;      // fused kq projection weights
    const float wqj = wq_p[jcol] * LOG2E;

    // per-lane x source: sample row = col16, channels kgrp*8..+7
    const float* xlane = x + ((size_t)b*T_*N_ + (n0 + col16))*C_ + kgrp*8;
    const int xstride = N_*C_;

    // zero h buf0
    for (int idx = tid; idx < 16*64/2; idx += 256) {
        ((int*)&hhi[0][0][0])[idx] = 0;
        ((int*)&hlo[0][0][0])[idx] = 0;
    }

    // ---- prologue: x-phase for step 0; prefetch x(1) ----
    floatx4 xR, xZ, xNI;               // x-projection accs, live across barrier
    {
        const float4 a = *(const float4*)xlane;
        const float4 c = *(const float4*)(xlane + 4);
        short8 ax_hi, ax_lo;
        split8v(a, c, ax_hi, ax_lo);
        xR  = MFMA16(ax_hi, wihH[0], bR4);
        xZ  = MFMA16(ax_hi, wihH[1], bZ4);
        xNI = MFMA16(ax_hi, wihH[2], bNI4);
        xR  = MFMA16(ax_hi, wihL[0], xR);
        xZ  = MFMA16(ax_hi, wihL[1], xZ);
        xNI = MFMA16(ax_hi, wihL[2], xNI);
        xR  = MFMA16(ax_lo, wihH[0], xR);
        xZ  = MFMA16(ax_lo, wihH[1], xZ);
        xNI = MFMA16(ax_lo, wihH[2], xNI);
    }
    float4 pAa = *(const float4*)(xlane + xstride);      // x(1) in flight
    float4 pAb = *(const float4*)(xlane + xstride + 4);
    float4 pBa = {0,0,0,0}, pBb = {0,0,0,0};
    BARRIER();

    float hp[4] = {0.f, 0.f, 0.f, 0.f};

// Region T: consume h(T-1) from LDS buf[CUR] + pre-seeded x-accs (step T);
// act(T); write h(T) to buf[CUR^1]; then compute x-phase of step T+1 from
// regs FXa/FXb (loaded one region ago) and issue the load of x(T+2) into
// GXa/GXb. x-phase MFMAs are register-only and overlap act/barrier/ds_read.
#define GRU_STEP(T, CUR, FXa, FXb, GXa, GXb) do {                               \
    const int nxt_ = (CUR) ^ 1;                                                 \
    short8 ah_hi[2], ah_lo[2];                                                  \
    _Pragma("unroll")                                                           \
    for (int kb = 0; kb < 2; ++kb) {                                            \
        const int ke = (kgrp*8 + kb*32) ^ ((col16 >> 2) << 4);                  \
        ah_hi[kb] = *(const short8*)&hhi[CUR][col16][ke];                       \
        ah_lo[kb] = *(const short8*)&hlo[CUR][col16][ke];                       \
    }                                                                           \
    /* h-phase: 6 chains; r/z seeded from x-phase accs (free combine) */        \
    floatx4 aRh0 = MFMA16(ah_hi[0], whhH[0][0], xR);                            \
    floatx4 aZh0 = MFMA16(ah_hi[0], whhH[1][0], xZ);                            \
    floatx4 aNH0 = MFMA16(ah_hi[0], whhH[2][0], bNH4);                          \
    floatx4 aRh1 = MFMA16(ah_hi[1], whhH[0][1], zero4);                         \
    floatx4 aZh1 = MFMA16(ah_hi[1], whhH[1][1], zero4);                         \
    floatx4 aNH1 = MFMA16(ah_hi[1], whhH[2][1], zero4);                         \
    aRh0 = MFMA16(ah_hi[0], whhL[0][0], aRh0);                                  \
    aZh0 = MFMA16(ah_hi[0], whhL[1][0], aZh0);                                  \
    aNH0 = MFMA16(ah_hi[0], whhL[2][0], aNH0);                                  \
    aRh1 = MFMA16(ah_hi[1], whhL[0][1], aRh1);                                  \
    aZh1 = MFMA16(ah_hi[1], whhL[1][1], aZh1);                                  \
    aNH1 = MFMA16(ah_hi[1], whhL[2][1], aNH1);                                  \
    aRh0 = MFMA16(ah_lo[0], whhH[0][0], aRh0);                                  \
    aZh0 = MFMA16(ah_lo[0], whhH[1][0], aZh0);                                  \
    aNH0 = MFMA16(ah_lo[0], whhH[2][0], aNH0);                                  \
    aRh1 = MFMA16(ah_lo[1], whhH[0][1], aRh1);                                  \
    aZh1 = MFMA16(ah_lo[1], whhH[1][1], aZh1);                                  \
    aNH1 = MFMA16(ah_lo[1], whhH[2][1], aNH1);                                  \
    /* activations (exp2-native) + pre-split h store; consumes xNI(T) */        \
    _Pragma("unroll")                                                           \
    for (int s = 0; s < 4; ++s) {                                               \
        const float rs = aRh0[s] + aRh1[s];                                     \
        const float zs = aZh0[s] + aZh1[s];                                     \
        const float nh = aNH0[s] + aNH1[s];                                     \
        const float tr = frcp(1.f + fexp2(rs));          /* = r   */            \
        const float v  = fmaf(tr, nh, xNI[s]);                                  \
        const float tn = frcp(1.f + fexp2(v));                                  \
        const float nn = fmaf(tn, -2.f, 1.f);            /* tanh */             \
        const float tw = frcp(1.f + fexp2(zs));          /* = 1-z */            \
        const float h  = fmaf(tw, nn - hp[s], hp[s]);                           \
        hp[s] = h;                                                              \
        const unsigned short hh = f2bf(h);                                      \
        const unsigned short hl = f2bf(h - bf16_f32(hh));                       \
        const int r = kgrp*4 + s;                                               \
        const int c = jcol ^ (kgrp << 4);                                       \
        hhi[nxt_][r][c] = (short)hh;                                            \
        hlo[nxt_][r][c] = (short)hl;                                            \
    }                                                                           \
    /* x-phase for step T+1: register-only, overlaps act/barrier/ds-wait */     \
    if ((T) + 1 < T_) {                                                         \
        short8 ax_hi, ax_lo;                                                    \
        split8v(FXa, FXb, ax_hi, ax_lo);                                        \
        xR  = MFMA16(ax_hi, wihH[0], bR4);                                      \
        xZ  = MFMA16(ax_hi, wihH[1], bZ4);                                      \
        xNI = MFMA16(ax_hi, wihH[2], bNI4);                                     \
        xR  = MFMA16(ax_hi, wihL[0], xR);                                       \
        xZ  = MFMA16(ax_hi, wihL[1], xZ);                                       \
        xNI = MFMA16(ax_hi, wihL[2], xNI);                                      \
        xR  = MFMA16(ax_lo, wihH[0], xR);                                       \
        xZ  = MFMA16(ax_lo, wihH[1], xZ);                                       \
        xNI = MFMA16(ax_lo, wihH[2], xNI);                                      \
    }                                                                           \
    if ((T) + 2 < T_) {  /* issue load x(T+2) */                                \
        GXa = *(const float4*)(xlane + (size_t)((T)+2) * xstride);              \
        GXb = *(const float4*)(xlane + (size_t)((T)+2) * xstride + 4);          \
    }                                                                           \
    BARRIER();                                                                  \
} while (0)

    for (int t = 0; t < T_; t += 2) {
        GRU_STEP(t,     0, pAa, pAb, pBa, pBb);
        GRU_STEP(t + 1, 1, pBa, pBb, pAa, pAb);
    }
#undef GRU_STEP

    // ---- fused key/query projection epilogue ----
    float kp[4], qp[4];
    #pragma unroll
    for (int s = 0; s < 4; ++s) { kp[s] = hp[s] * wkj; qp[s] = hp[s] * wqj; }
    #pragma unroll
    for (int mask = 8; mask; mask >>= 1) {
        #pragma unroll
        for (int s = 0; s < 4; ++s) {
            kp[s] += __shfl_xor(kp[s], mask);
            qp[s] += __shfl_xor(qp[s], mask);
        }
    }
    if (col16 == 0) {
        #pragma unroll
        for (int s = 0; s < 4; ++s) {
            kq_lds[0][kgrp*4 + s][w] = kp[s];
            kq_lds[1][kgrp*4 + s][w] = qp[s];
        }
    }
    __syncthreads();
    if (tid < 32) {
        const int smp = tid & 15, sel = tid >> 4;
        const float v = kq_lds[sel][smp][0] + kq_lds[sel][smp][1]
                      + kq_lds[sel][smp][2] + kq_lds[sel][smp][3];
        (sel ? query : key)[m0 + smp] = v;
    }
}

// den stores rcp(sum_j exp2(lrelu(ki+qj))).  No max-shift needed: scores are
// small (|k|,|q| <~ 2) -> exp2 args far inside fp32 range.
__global__ __launch_bounds__(256) void den_kernel(
    const float* __restrict__ key, const float* __restrict__ query,
    float* __restrict__ den)
{
    int idx  = (blockIdx.x * 256 + threadIdx.x) >> 6;   // b*2048 + i
    int lane = threadIdx.x & 63;
    int b    = idx >> 11;
    float ki = key[idx];
    const float4* q4 = (const float4*)(query + ((size_t)b << 11));
    float sum = 0.f;
    for (int jj = lane; jj < N_/4; jj += 64) {
        float4 qv = q4[jj];
        sum += fexp2(lrelu(ki + qv.x)) + fexp2(lrelu(ki + qv.y))
             + fexp2(lrelu(ki + qv.z)) + fexp2(lrelu(ki + qv.w));
    }
    #pragma unroll
    for (int off = 32; off; off >>= 1) sum += __shfl_down(sum, off);
    if (lane == 0) den[idx] = frcp(sum);
}

// adj[i][j] = 0.125 * sum_b (attn[b][i][j] + attn[b][j][i]); float4 over j
__global__ __launch_bounds__(256) void out_kernel(
    const float* __restrict__ key, const float* __restrict__ query,
    const float* __restrict__ den, float* __restrict__ out)
{
    const int flat = blockIdx.x * 256 + threadIdx.x;   // N*N/4 float4 elems
    const int i  = flat >> 9;            // row (wave-uniform within block)
    const int j0 = (flat & 511) << 2;    // first of 4 cols
    float4 acc = {0.f, 0.f, 0.f, 0.f};
    #pragma unroll
    for (int b = 0; b < B_; ++b) {
        const int bi = (b << 11) + i, bj = (b << 11) + j0;
        const float ki = key[bi], qi = query[bi], di = den[bi];
        const float4 k4 = *(const float4*)&key[bj];
        const float4 q4 = *(const float4*)&query[bj];
        const float4 d4 = *(const float4*)&den[bj];
        acc.x = fmaf(fexp2(lrelu(ki + q4.x)), di, acc.x);
        acc.y = fmaf(fexp2(lrelu(ki + q4.y)), di, acc.y);
        acc.z = fmaf(fexp2(lrelu(ki + q4.z)), di, acc.z);
        acc.w = fmaf(fexp2(lrelu(ki + q4.w)), di, acc.w);
        acc.x = fmaf(fexp2(lrelu(k4.x + qi)), d4.x, acc.x);
        acc.y = fmaf(fexp2(lrelu(k4.y + qi)), d4.y, acc.y);
        acc.z = fmaf(fexp2(lrelu(k4.z + qi)), d4.z, acc.z);
        acc.w = fmaf(fexp2(lrelu(k4.w + qi)), d4.w, acc.w);
    }
    acc.x *= 0.125f; acc.y *= 0.125f; acc.z *= 0.125f; acc.w *= 0.125f;
    ((float4*)out)[flat] = acc;
}

extern "C" void kernel_launch(void* const* d_in, const int* in_sizes, int n_in,
                              void* d_out, int out_size, void* d_ws, size_t ws_size,
                              hipStream_t stream) {
    const float* x    = (const float*)d_in[0];
    const float* w_ih = (const float*)d_in[1];
    const float* w_hh = (const float*)d_in[2];
    const float* b_ih = (const float*)d_in[3];
    const float* b_hh = (const float*)d_in[4];
    const float* wk   = (const float*)d_in[5];
    const float* wq   = (const float*)d_in[6];
    float* out = (float*)d_out;
    float* ws  = (float*)d_ws;

    float* key   = ws;             // 8192
    float* query = ws + 8192;      // 8192
    float* den   = ws + 16384;     // 8192

    gru_kernel<<<M_/16, 256, 0, stream>>>(x, w_ih, w_hh, b_ih, b_hh,
                                          wk, wq, key, query);
    den_kernel<<<M_/4, 256, 0, stream>>>(key, query, den);
    out_kernel<<<(N_*N_/4)/256, 256, 0, stream>>>(key, query, den, out);
}

// Round 13
// 77.195 us; speedup vs baseline: 1.7972x; 1.0722x over previous
//
#include <hip/hip_runtime.h>
#include <hip/hip_bf16.h>
#include <math.h>

#define B_ 4
#define T_ 64
#define N_ 2048
#define C_ 32
#define H_ 64
#define M_ (B_*N_)      // 8192
#define SLOPE 0.2f
#define LOG2E 1.44269504088896340736f

typedef __attribute__((ext_vector_type(8))) short short8;   // 8 bf16 (4 VGPRs)
typedef __attribute__((ext_vector_type(4))) float floatx4;  // MFMA acc

#define MFMA16(a,b,c) __builtin_amdgcn_mfma_f32_16x16x32_bf16(a,b,c,0,0,0)

// Barrier without vmcnt drain: LDS visibility via lgkmcnt(0); global prefetch
// loads stay in flight. Uniform control flow at every use.
#define BARRIER() asm volatile("s_waitcnt lgkmcnt(0)\n\ts_barrier" ::: "memory")

__device__ __forceinline__ float lrelu(float v) { return fmaxf(v, SLOPE * v); }
__device__ __forceinline__ float frcp(float x)  { return __builtin_amdgcn_rcpf(x); }
__device__ __forceinline__ float fexp2(float x) { float r; asm("v_exp_f32 %0, %1" : "=v"(r) : "v"(x)); return r; }

__device__ __forceinline__ unsigned short f2bf(float f) {
    union { __hip_bfloat16 b; unsigned short u; } cv;
    cv.b = __float2bfloat16(f);          // HW cvt (RNE)
    return cv.u;
}
__device__ __forceinline__ float bf16_f32(unsigned short s) {
    return __uint_as_float(((unsigned)s) << 16);
}
// 8 fp32 (scaled) -> COMPENSATED bf16 hi/lo pair (weights only; setup cost)
__device__ __forceinline__ void split8s(const float* f, float sc, short8& hi, short8& lo) {
    short8 h, l;
    #pragma unroll
    for (int e = 0; e < 8; ++e) {
        const float v = f[e] * sc;
        const unsigned short hh = f2bf(v);
        const unsigned short ll = f2bf(v - bf16_f32(hh));
        h[e] = (short)hh; l[e] = (short)ll;
    }
    hi = h; lo = l;
}
// 8 fp32 -> plain bf16 (x operands; lo term dropped — error budget analysis
// in round-13 notes: operand-lo contributes <3e-6 to final adj absmax)
__device__ __forceinline__ short8 cvt8(float4 a, float4 b) {
    const float f[8] = {a.x,a.y,a.z,a.w,b.x,b.y,b.z,b.w};
    short8 h;
    #pragma unroll
    for (int e = 0; e < 8; ++e) h[e] = (short)f2bf(f[e]);
    return h;
}

// ---------------- GRU kernel (fused kq; bf16-hi operands) ----------------
// 512 blocks x 256 threads (4 waves) = 2 blocks/CU = 2 waves/SIMD.
// Block owns 16 samples; wave w owns gate-cols [w*16, w*16+16) of r,z,n.
// h state: registers stay fp32 (exact recurrence); LDS copy for the gh matmul
// is bf16-hi only [2][16][64], col-swizzle c^((r>>2)<<4). Weight fragments
// keep the hi/lo compensation (free: pinned in regs) -> per (gate,kb) the
// h-phase is 2 MFMAs: ah*wH + ah*wL. 18 MFMA/wave-step total (6 x-phase
// shadowed + 12 h-phase).
__global__ __launch_bounds__(256, 2) void gru_kernel(
    const float* __restrict__ x,      // [B,T,N,C]
    const float* __restrict__ w_ih,   // [192][32]
    const float* __restrict__ w_hh,   // [192][64]
    const float* __restrict__ b_ih,   // [192]
    const float* __restrict__ b_hh,   // [192]
    const float* __restrict__ wk_p,   // [64]
    const float* __restrict__ wq_p,   // [64]
    float* __restrict__ key,          // [M]  (log2e-scaled)
    float* __restrict__ query)        // [M]  (log2e-scaled)
{
    __shared__ __align__(16) short hhi[2][16][64];   // 4 KB
    __shared__ float kq_lds[2][16][4];               // [k/q][sample][wave]

    const int tid   = threadIdx.x;
    const int lane  = tid & 63;
    const int w     = tid >> 6;        // wave 0..3
    const int col16 = lane & 15;
    const int kgrp  = lane >> 4;       // 0..3

    const int m0 = blockIdx.x * 16;
    const int b  = m0 >> 11;
    const int n0 = m0 & 2047;

    // Gate scales folded into weights/biases:
    //  r: -log2e (r = rcp(1+exp2(aR))); z: +log2e (1-z = rcp(1+exp2(aZ)));
    //  n: 2*log2e (tanh(v) = 1-2*rcp(1+exp2(2*log2e*v)))
    const float gsc[3] = {-LOG2E, LOG2E, 2.f*LOG2E};

    // Weight B-fragments (compensated hi/lo): B[k][col]=w[col][k]
    short8 whhH[3][2], whhL[3][2];   // [gate][kb]
    short8 wihH[3],    wihL[3];
    #pragma unroll
    for (int g = 0; g < 3; ++g) {
        const int rw = g*64 + w*16 + col16;
        #pragma unroll
        for (int kb = 0; kb < 2; ++kb)
            split8s(w_hh + rw*64 + kb*32 + kgrp*8, gsc[g], whhH[g][kb], whhL[g][kb]);
        split8s(w_ih + rw*32 + kgrp*8, gsc[g], wihH[g], wihL[g]);
    }
    const int jcol = w*16 + col16;
    const float br  = -LOG2E     * (b_ih[jcol]    + b_hh[jcol]);
    const float bz  =  LOG2E     * (b_ih[64+jcol] + b_hh[64+jcol]);
    const float bin =  2.f*LOG2E * b_ih[128+jcol];
    const float bhn =  2.f*LOG2E * b_hh[128+jcol];
    const floatx4 bR4  = {br, br, br, br};     // persistent C-operand seeds
    const floatx4 bZ4  = {bz, bz, bz, bz};
    const floatx4 bNI4 = {bin, bin, bin, bin};
    const floatx4 bNH4 = {bhn, bhn, bhn, bhn};
    const floatx4 zero4 = {0.f, 0.f, 0.f, 0.f};

    const float wkj = wk_p[jcol] * LOG2E;      // fused kq projection weights
    const float wqj = wq_p[jcol] * LOG2E;

    // per-lane x source: sample row = col16, channels kgrp*8..+7
    const float* xlane = x + ((size_t)b*T_*N_ + (n0 + col16))*C_ + kgrp*8;
    const int xstride = N_*C_;

    // zero h buf0
    for (int idx = tid; idx < 16*64/2; idx += 256)
        ((int*)&hhi[0][0][0])[idx] = 0;

    // ---- prologue: x-phase for step 0; prefetch x(1) ----
    floatx4 xR, xZ, xNI;               // x-projection accs, live across barrier
    {
        const short8 ax = cvt8(*(const float4*)xlane, *(const float4*)(xlane + 4));
        xR  = MFMA16(ax, wihH[0], bR4);
        xZ  = MFMA16(ax, wihH[1], bZ4);
        xNI = MFMA16(ax, wihH[2], bNI4);
        xR  = MFMA16(ax, wihL[0], xR);
        xZ  = MFMA16(ax, wihL[1], xZ);
        xNI = MFMA16(ax, wihL[2], xNI);
    }
    float4 pAa = *(const float4*)(xlane + xstride);      // x(1) in flight
    float4 pAb = *(const float4*)(xlane + xstride + 4);
    float4 pBa = {0,0,0,0}, pBb = {0,0,0,0};
    BARRIER();

    float hp[4] = {0.f, 0.f, 0.f, 0.f};

// Region T: consume h(T-1) from LDS buf[CUR] + pre-seeded x-accs (step T);
// act(T); write h(T) to buf[CUR^1]; then x-phase of step T+1 (register-only,
// overlaps act/barrier/next ds_read) and issue load of x(T+2).
#define GRU_STEP(T, CUR, FXa, FXb, GXa, GXb) do {                               \
    const int nxt_ = (CUR) ^ 1;                                                 \
    short8 ah[2];                                                               \
    _Pragma("unroll")                                                           \
    for (int kb = 0; kb < 2; ++kb) {                                            \
        const int ke = (kgrp*8 + kb*32) ^ ((col16 >> 2) << 4);                  \
        ah[kb] = *(const short8*)&hhi[CUR][col16][ke];                          \
    }                                                                           \
    /* h-phase: 6 chains of depth 2 (weight hi/lo compensation) */              \
    __builtin_amdgcn_s_setprio(1);                                              \
    floatx4 aRh0 = MFMA16(ah[0], whhH[0][0], xR);                               \
    floatx4 aZh0 = MFMA16(ah[0], whhH[1][0], xZ);                               \
    floatx4 aNH0 = MFMA16(ah[0], whhH[2][0], bNH4);                             \
    floatx4 aRh1 = MFMA16(ah[1], whhH[0][1], zero4);                            \
    floatx4 aZh1 = MFMA16(ah[1], whhH[1][1], zero4);                            \
    floatx4 aNH1 = MFMA16(ah[1], whhH[2][1], zero4);                            \
    aRh0 = MFMA16(ah[0], whhL[0][0], aRh0);                                     \
    aZh0 = MFMA16(ah[0], whhL[1][0], aZh0);                                     \
    aNH0 = MFMA16(ah[0], whhL[2][0], aNH0);                                     \
    aRh1 = MFMA16(ah[1], whhL[0][1], aRh1);                                     \
    aZh1 = MFMA16(ah[1], whhL[1][1], aZh1);                                     \
    aNH1 = MFMA16(ah[1], whhL[2][1], aNH1);                                     \
    __builtin_amdgcn_s_setprio(0);                                              \
    /* activations (exp2-native) + bf16 h store; hp[] stays fp32 */             \
    _Pragma("unroll")                                                           \
    for (int s = 0; s < 4; ++s) {                                               \
        const float rs = aRh0[s] + aRh1[s];                                     \
        const float zs = aZh0[s] + aZh1[s];                                     \
        const float nh = aNH0[s] + aNH1[s];                                     \
        const float tr = frcp(1.f + fexp2(rs));          /* = r   */            \
        const float v  = fmaf(tr, nh, xNI[s]);                                  \
        const float tn = frcp(1.f + fexp2(v));                                  \
        const float nn = fmaf(tn, -2.f, 1.f);            /* tanh */             \
        const float tw = frcp(1.f + fexp2(zs));          /* = 1-z */            \
        const float h  = fmaf(tw, nn - hp[s], hp[s]);                           \
        hp[s] = h;                                                              \
        const int r = kgrp*4 + s;                                               \
        const int c = jcol ^ (kgrp << 4);                                       \
        hhi[nxt_][r][c] = (short)f2bf(h);                                       \
    }                                                                           \
    /* x-phase for step T+1: register-only, overlaps act/barrier/ds-wait */     \
    if ((T) + 1 < T_) {                                                         \
        const short8 ax = cvt8(FXa, FXb);                                       \
        xR  = MFMA16(ax, wihH[0], bR4);                                         \
        xZ  = MFMA16(ax, wihH[1], bZ4);                                         \
        xNI = MFMA16(ax, wihH[2], bNI4);                                        \
        xR  = MFMA16(ax, wihL[0], xR);                                          \
        xZ  = MFMA16(ax, wihL[1], xZ);                                          \
        xNI = MFMA16(ax, wihL[2], xNI);                                         \
    }                                                                           \
    if ((T) + 2 < T_) {  /* issue load x(T+2) */                                \
        GXa = *(const float4*)(xlane + (size_t)((T)+2) * xstride);              \
        GXb = *(const float4*)(xlane + (size_t)((T)+2) * xstride + 4);          \
    }                                                                           \
    BARRIER();                                                                  \
} while (0)

    for (int t = 0; t < T_; t += 2) {
        GRU_STEP(t,     0, pAa, pAb, pBa, pBb);
        GRU_STEP(t + 1, 1, pBa, pBb, pAa, pAb);
    }
#undef GRU_STEP

    // ---- fused key/query projection epilogue ----
    float kp[4], qp[4];
    #pragma unroll
    for (int s = 0; s < 4; ++s) { kp[s] = hp[s] * wkj; qp[s] = hp[s] * wqj; }
    #pragma unroll
    for (int mask = 8; mask; mask >>= 1) {
        #pragma unroll
        for (int s = 0; s < 4; ++s) {
            kp[s] += __shfl_xor(kp[s], mask);
            qp[s] += __shfl_xor(qp[s], mask);
        }
    }
    if (col16 == 0) {
        #pragma unroll
        for (int s = 0; s < 4; ++s) {
            kq_lds[0][kgrp*4 + s][w] = kp[s];
            kq_lds[1][kgrp*4 + s][w] = qp[s];
        }
    }
    __syncthreads();
    if (tid < 32) {
        const int smp = tid & 15, sel = tid >> 4;
        const float v = kq_lds[sel][smp][0] + kq_lds[sel][smp][1]
                      + kq_lds[sel][smp][2] + kq_lds[sel][smp][3];
        (sel ? query : key)[m0 + smp] = v;
    }
}

// den stores rcp(sum_j exp2(lrelu(ki+qj))).  No max-shift needed: scores are
// small (|k|,|q| <~ 2) -> exp2 args far inside fp32 range.
__global__ __launch_bounds__(256) void den_kernel(
    const float* __restrict__ key, const float* __restrict__ query,
    float* __restrict__ den)
{
    int idx  = (blockIdx.x * 256 + threadIdx.x) >> 6;   // b*2048 + i
    int lane = threadIdx.x & 63;
    int b    = idx >> 11;
    float ki = key[idx];
    const float4* q4 = (const float4*)(query + ((size_t)b << 11));
    float sum = 0.f;
    for (int jj = lane; jj < N_/4; jj += 64) {
        float4 qv = q4[jj];
        sum += fexp2(lrelu(ki + qv.x)) + fexp2(lrelu(ki + qv.y))
             + fexp2(lrelu(ki + qv.z)) + fexp2(lrelu(ki + qv.w));
    }
    #pragma unroll
    for (int off = 32; off; off >>= 1) sum += __shfl_down(sum, off);
    if (lane == 0) den[idx] = frcp(sum);
}

// adj[i][j] = 0.125 * sum_b (attn[b][i][j] + attn[b][j][i]); float4 over j
__global__ __launch_bounds__(256) void out_kernel(
    const float* __restrict__ key, const float* __restrict__ query,
    const float* __restrict__ den, float* __restrict__ out)
{
    const int flat = blockIdx.x * 256 + threadIdx.x;   // N*N/4 float4 elems
    const int i  = flat >> 9;            // row (wave-uniform within block)
    const int j0 = (flat & 511) << 2;    // first of 4 cols
    float4 acc = {0.f, 0.f, 0.f, 0.f};
    #pragma unroll
    for (int b = 0; b < B_; ++b) {
        const int bi = (b << 11) + i, bj = (b << 11) + j0;
        const float ki = key[bi], qi = query[bi], di = den[bi];
        const float4 k4 = *(const float4*)&key[bj];
        const float4 q4 = *(const float4*)&query[bj];
        const float4 d4 = *(const float4*)&den[bj];
        acc.x = fmaf(fexp2(lrelu(ki + q4.x)), di, acc.x);
        acc.y = fmaf(fexp2(lrelu(ki + q4.y)), di, acc.y);
        acc.z = fmaf(fexp2(lrelu(ki + q4.z)), di, acc.z);
        acc.w = fmaf(fexp2(lrelu(ki + q4.w)), di, acc.w);
        acc.x = fmaf(fexp2(lrelu(k4.x + qi)), d4.x, acc.x);
        acc.y = fmaf(fexp2(lrelu(k4.y + qi)), d4.y, acc.y);
        acc.z = fmaf(fexp2(lrelu(k4.z + qi)), d4.z, acc.z);
        acc.w = fmaf(fexp2(lrelu(k4.w + qi)), d4.w, acc.w);
    }
    acc.x *= 0.125f; acc.y *= 0.125f; acc.z *= 0.125f; acc.w *= 0.125f;
    ((float4*)out)[flat] = acc;
}

extern "C" void kernel_launch(void* const* d_in, const int* in_sizes, int n_in,
                              void* d_out, int out_size, void* d_ws, size_t ws_size,
                              hipStream_t stream) {
    const float* x    = (const float*)d_in[0];
    const float* w_ih = (const float*)d_in[1];
    const float* w_hh = (const float*)d_in[2];
    const float* b_ih = (const float*)d_in[3];
    const float* b_hh = (const float*)d_in[4];
    const float* wk   = (const float*)d_in[5];
    const float* wq   = (const float*)d_in[6];
    float* out = (float*)d_out;
    float* ws  = (float*)d_ws;

    float* key   = ws;             // 8192
    float* query = ws + 8192;      // 8192
    float* den   = ws + 16384;     // 8192

    gru_kernel<<<M_/16, 256, 0, stream>>>(x, w_ih, w_hh, b_ih, b_hh,
                                          wk, wq, key, query);
    den_kernel<<<M_/4, 256, 0, stream>>>(key, query, den);
    out_kernel<<<(N_*N_/4)/256, 256, 0, stream>>>(key, query, den, out);
}

// Round 14
// 69.041 us; speedup vs baseline: 2.0094x; 1.1181x over previous
//
#include <hip/hip_runtime.h>
#include <math.h>

#define B_ 4
#define T_ 64
#define N_ 2048
#define C_ 32
#define H_ 64
#define M_ (B_*N_)      // 8192
#define SLOPE 0.2f
#define LOG2E 1.44269504088896340736f

typedef __attribute__((ext_vector_type(8))) _Float16 half8;  // 8 f16 (4 VGPRs)
typedef __attribute__((ext_vector_type(4))) float floatx4;   // MFMA acc

#define MFMA16H(a,b,c) __builtin_amdgcn_mfma_f32_16x16x32_f16(a,b,c,0,0,0)

// Barrier without vmcnt drain: LDS visibility via lgkmcnt(0); global prefetch
// loads stay in flight. Uniform control flow at every use.
#define BARRIER() asm volatile("s_waitcnt lgkmcnt(0)\n\ts_barrier" ::: "memory")

__device__ __forceinline__ float lrelu(float v) { return fmaxf(v, SLOPE * v); }
__device__ __forceinline__ float frcp(float x)  { return __builtin_amdgcn_rcpf(x); }
__device__ __forceinline__ float fexp2(float x) { float r; asm("v_exp_f32 %0, %1" : "=v"(r) : "v"(x)); return r; }

// 8 fp32 -> fp16 fragment. fp16 (e5m10) rel err 2.4e-4 — 8x better than the
// bf16-hi scheme this replaces; no compensation terms needed anywhere.
__device__ __forceinline__ half8 cvt8h(float4 a, float4 b) {
    half8 h;
    h[0]=(_Float16)a.x; h[1]=(_Float16)a.y; h[2]=(_Float16)a.z; h[3]=(_Float16)a.w;
    h[4]=(_Float16)b.x; h[5]=(_Float16)b.y; h[6]=(_Float16)b.z; h[7]=(_Float16)b.w;
    return h;
}
__device__ __forceinline__ half8 cvt8s(const float* f, float sc) {
    half8 h;
    #pragma unroll
    for (int e = 0; e < 8; ++e) h[e] = (_Float16)(f[e] * sc);
    return h;
}

// ---------------- GRU kernel (fused kq; pure-fp16 matmul) ----------------
// 512 blocks x 256 threads (4 waves) = 2 blocks/CU = 2 waves/SIMD.
// Block owns 16 samples; wave w owns gate-cols [w*16, w*16+16) of r,z,n.
// h recurrence stays fp32 in registers; the LDS copy for the gh matmul is
// fp16 [2][16][64], col-swizzle c^((r>>2)<<4). Weights/x fp16, uncompensated.
// 9 MFMA/wave-step: 6 h-phase (3 gate chains, depth 2) + 3 x-phase (shadowed
// into the previous region: overlaps act/barrier/ds-wait).
__global__ __launch_bounds__(256, 2) void gru_kernel(
    const float* __restrict__ x,      // [B,T,N,C]
    const float* __restrict__ w_ih,   // [192][32]
    const float* __restrict__ w_hh,   // [192][64]
    const float* __restrict__ b_ih,   // [192]
    const float* __restrict__ b_hh,   // [192]
    const float* __restrict__ wk_p,   // [64]
    const float* __restrict__ wq_p,   // [64]
    float* __restrict__ key,          // [M]  (log2e-scaled)
    float* __restrict__ query)        // [M]  (log2e-scaled)
{
    __shared__ __align__(16) _Float16 hh[2][16][64];   // 4 KB
    __shared__ float kq_lds[2][16][4];                 // [k/q][sample][wave]

    const int tid   = threadIdx.x;
    const int lane  = tid & 63;
    const int w     = tid >> 6;        // wave 0..3
    const int col16 = lane & 15;
    const int kgrp  = lane >> 4;       // 0..3

    const int m0 = blockIdx.x * 16;
    const int b  = m0 >> 11;
    const int n0 = m0 & 2047;

    // Gate scales folded into weights/biases:
    //  r: -log2e (r = rcp(1+exp2(aR))); z: +log2e (1-z = rcp(1+exp2(aZ)));
    //  n: 2*log2e (tanh(v) = 1-2*rcp(1+exp2(2*log2e*v)))
    const float gsc[3] = {-LOG2E, LOG2E, 2.f*LOG2E};

    // Weight B-fragments (plain fp16): B[k][col]=w[col][k]
    half8 whhF[3][2];   // [gate][kb]
    half8 wihF[3];
    #pragma unroll
    for (int g = 0; g < 3; ++g) {
        const int rw = g*64 + w*16 + col16;
        #pragma unroll
        for (int kb = 0; kb < 2; ++kb)
            whhF[g][kb] = cvt8s(w_hh + rw*64 + kb*32 + kgrp*8, gsc[g]);
        wihF[g] = cvt8s(w_ih + rw*32 + kgrp*8, gsc[g]);
    }
    const int jcol = w*16 + col16;
    const float br  = -LOG2E     * (b_ih[jcol]    + b_hh[jcol]);
    const float bz  =  LOG2E     * (b_ih[64+jcol] + b_hh[64+jcol]);
    const float bin =  2.f*LOG2E * b_ih[128+jcol];
    const float bhn =  2.f*LOG2E * b_hh[128+jcol];
    const floatx4 bR4  = {br, br, br, br};     // persistent C-operand seeds
    const floatx4 bZ4  = {bz, bz, bz, bz};
    const floatx4 bNI4 = {bin, bin, bin, bin};
    const floatx4 bNH4 = {bhn, bhn, bhn, bhn};

    const float wkj = wk_p[jcol] * LOG2E;      // fused kq projection weights
    const float wqj = wq_p[jcol] * LOG2E;

    // per-lane x source: sample row = col16, channels kgrp*8..+7
    const float* xlane = x + ((size_t)b*T_*N_ + (n0 + col16))*C_ + kgrp*8;
    const int xstride = N_*C_;

    // zero h buf0
    for (int idx = tid; idx < 16*64/2; idx += 256)
        ((int*)&hh[0][0][0])[idx] = 0;

    // ---- prologue: x-phase for step 0; prefetch x(1) ----
    floatx4 xR, xZ, xNI;               // x-projection accs, live across barrier
    {
        const half8 ax = cvt8h(*(const float4*)xlane, *(const float4*)(xlane + 4));
        xR  = MFMA16H(ax, wihF[0], bR4);
        xZ  = MFMA16H(ax, wihF[1], bZ4);
        xNI = MFMA16H(ax, wihF[2], bNI4);
    }
    float4 pAa = *(const float4*)(xlane + xstride);      // x(1) in flight
    float4 pAb = *(const float4*)(xlane + xstride + 4);
    float4 pBa = {0,0,0,0}, pBb = {0,0,0,0};
    BARRIER();

    float hp[4] = {0.f, 0.f, 0.f, 0.f};

// Region T: consume h(T-1) from LDS buf[CUR] + pre-seeded x-accs (step T);
// act(T); write h(T) to buf[CUR^1]; then x-phase of step T+1 (register-only,
// overlaps act/barrier/next ds_read) and issue load of x(T+2).
#define GRU_STEP(T, CUR, FXa, FXb, GXa, GXb) do {                               \
    const int nxt_ = (CUR) ^ 1;                                                 \
    half8 ah[2];                                                                \
    _Pragma("unroll")                                                           \
    for (int kb = 0; kb < 2; ++kb) {                                            \
        const int ke = (kgrp*8 + kb*32) ^ ((col16 >> 2) << 4);                  \
        ah[kb] = *(const half8*)&hh[CUR][col16][ke];                            \
    }                                                                           \
    /* h-phase: 3 gate chains, depth 2 (kb0 -> kb1); r/z seeded from x-accs */  \
    __builtin_amdgcn_s_setprio(1);                                              \
    floatx4 aR  = MFMA16H(ah[0], whhF[0][0], xR);                               \
    floatx4 aZ  = MFMA16H(ah[0], whhF[1][0], xZ);                               \
    floatx4 aNH = MFMA16H(ah[0], whhF[2][0], bNH4);                             \
    aR  = MFMA16H(ah[1], whhF[0][1], aR);                                       \
    aZ  = MFMA16H(ah[1], whhF[1][1], aZ);                                       \
    aNH = MFMA16H(ah[1], whhF[2][1], aNH);                                      \
    __builtin_amdgcn_s_setprio(0);                                              \
    /* activations (exp2-native) + fp16 h store; hp[] stays fp32 */             \
    _Pragma("unroll")                                                           \
    for (int s = 0; s < 4; ++s) {                                               \
        const float tr = frcp(1.f + fexp2(aR[s]));        /* = r   */           \
        const float v  = fmaf(tr, aNH[s], xNI[s]);                              \
        const float tn = frcp(1.f + fexp2(v));                                  \
        const float nn = fmaf(tn, -2.f, 1.f);             /* tanh */            \
        const float tw = frcp(1.f + fexp2(aZ[s]));        /* = 1-z */           \
        const float h  = fmaf(tw, nn - hp[s], hp[s]);                           \
        hp[s] = h;                                                              \
        const int r = kgrp*4 + s;                                               \
        const int c = jcol ^ (kgrp << 4);                                       \
        hh[nxt_][r][c] = (_Float16)h;                                           \
    }                                                                           \
    /* x-phase for step T+1: register-only, overlaps act/barrier/ds-wait */     \
    if ((T) + 1 < T_) {                                                         \
        const half8 ax = cvt8h(FXa, FXb);                                       \
        xR  = MFMA16H(ax, wihF[0], bR4);                                        \
        xZ  = MFMA16H(ax, wihF[1], bZ4);                                        \
        xNI = MFMA16H(ax, wihF[2], bNI4);                                       \
    }                                                                           \
    if ((T) + 2 < T_) {  /* issue load x(T+2) */                                \
        GXa = *(const float4*)(xlane + (size_t)((T)+2) * xstride);              \
        GXb = *(const float4*)(xlane + (size_t)((T)+2) * xstride + 4);          \
    }                                                                           \
    BARRIER();                                                                  \
} while (0)

    for (int t = 0; t < T_; t += 2) {
        GRU_STEP(t,     0, pAa, pAb, pBa, pBb);
        GRU_STEP(t + 1, 1, pBa, pBb, pAa, pAb);
    }
#undef GRU_STEP

    // ---- fused key/query projection epilogue ----
    float kp[4], qp[4];
    #pragma unroll
    for (int s = 0; s < 4; ++s) { kp[s] = hp[s] * wkj; qp[s] = hp[s] * wqj; }
    #pragma unroll
    for (int mask = 8; mask; mask >>= 1) {
        #pragma unroll
        for (int s = 0; s < 4; ++s) {
            kp[s] += __shfl_xor(kp[s], mask);
            qp[s] += __shfl_xor(qp[s], mask);
        }
    }
    if (col16 == 0) {
        #pragma unroll
        for (int s = 0; s < 4; ++s) {
            kq_lds[0][kgrp*4 + s][w] = kp[s];
            kq_lds[1][kgrp*4 + s][w] = qp[s];
        }
    }
    __syncthreads();
    if (tid < 32) {
        const int smp = tid & 15, sel = tid >> 4;
        const float v = kq_lds[sel][smp][0] + kq_lds[sel][smp][1]
                      + kq_lds[sel][smp][2] + kq_lds[sel][smp][3];
        (sel ? query : key)[m0 + smp] = v;
    }
}

// den stores rcp(sum_j exp2(lrelu(ki+qj))).  No max-shift needed: scores are
// small (|k|,|q| <~ 2) -> exp2 args far inside fp32 range.
__global__ __launch_bounds__(256) void den_kernel(
    const float* __restrict__ key, const float* __restrict__ query,
    float* __restrict__ den)
{
    int idx  = (blockIdx.x * 256 + threadIdx.x) >> 6;   // b*2048 + i
    int lane = threadIdx.x & 63;
    int b    = idx >> 11;
    float ki = key[idx];
    const float4* q4 = (const float4*)(query + ((size_t)b << 11));
    float sum = 0.f;
    for (int jj = lane; jj < N_/4; jj += 64) {
        float4 qv = q4[jj];
        sum += fexp2(lrelu(ki + qv.x)) + fexp2(lrelu(ki + qv.y))
             + fexp2(lrelu(ki + qv.z)) + fexp2(lrelu(ki + qv.w));
    }
    #pragma unroll
    for (int off = 32; off; off >>= 1) sum += __shfl_down(sum, off);
    if (lane == 0) den[idx] = frcp(sum);
}

// adj[i][j] = 0.125 * sum_b (attn[b][i][j] + attn[b][j][i]); float4 over j
__global__ __launch_bounds__(256) void out_kernel(
    const float* __restrict__ key, const float* __restrict__ query,
    const float* __restrict__ den, float* __restrict__ out)
{
    const int flat = blockIdx.x * 256 + threadIdx.x;   // N*N/4 float4 elems
    const int i  = flat >> 9;            // row (wave-uniform within block)
    const int j0 = (flat & 511) << 2;    // first of 4 cols
    float4 acc = {0.f, 0.f, 0.f, 0.f};
    #pragma unroll
    for (int b = 0; b < B_; ++b) {
        const int bi = (b << 11) + i, bj = (b << 11) + j0;
        const float ki = key[bi], qi = query[bi], di = den[bi];
        const float4 k4 = *(const float4*)&key[bj];
        const float4 q4 = *(const float4*)&query[bj];
        const float4 d4 = *(const float4*)&den[bj];
        acc.x = fmaf(fexp2(lrelu(ki + q4.x)), di, acc.x);
        acc.y = fmaf(fexp2(lrelu(ki + q4.y)), di, acc.y);
        acc.z = fmaf(fexp2(lrelu(ki + q4.z)), di, acc.z);
        acc.w = fmaf(fexp2(lrelu(ki + q4.w)), di, acc.w);
        acc.x = fmaf(fexp2(lrelu(k4.x + qi)), d4.x, acc.x);
        acc.y = fmaf(fexp2(lrelu(k4.y + qi)), d4.y, acc.y);
        acc.z = fmaf(fexp2(lrelu(k4.z + qi)), d4.z, acc.z);
        acc.w = fmaf(fexp2(lrelu(k4.w + qi)), d4.w, acc.w);
    }
    acc.x *= 0.125f; acc.y *= 0.125f; acc.z *= 0.125f; acc.w *= 0.125f;
    ((float4*)out)[flat] = acc;
}

extern "C" void kernel_launch(void* const* d_in, const int* in_sizes, int n_in,
                              void* d_out, int out_size, void* d_ws, size_t ws_size,
                              hipStream_t stream) {
    const float* x    = (const float*)d_in[0];
    const float* w_ih = (const float*)d_in[1];
    const float* w_hh = (const float*)d_in[2];
    const float* b_ih = (const float*)d_in[3];
    const float* b_hh = (const float*)d_in[4];
    const float* wk   = (const float*)d_in[5];
    const float* wq   = (const float*)d_in[6];
    float* out = (float*)d_out;
    float* ws  = (float*)d_ws;

    float* key   = ws;             // 8192
    float* query = ws + 8192;      // 8192
    float* den   = ws + 16384;     // 8192

    gru_kernel<<<M_/16, 256, 0, stream>>>(x, w_ih, w_hh, b_ih, b_hh,
                                          wk, wq, key, query);
    den_kernel<<<M_/4, 256, 0, stream>>>(key, query, den);
    out_kernel<<<(N_*N_/4)/256, 256, 0, stream>>>(key, query, den, out);
}